// Round 2
// baseline (46060.806 us; speedup 1.0000x reference)
//
#include <hip/hip_runtime.h>

// CfC decoder on MI355X: one persistent kernel (256 blocks x 256 threads, all
// co-resident) runs the whole 128-step scan; grid-wide phases separated by a
// sense-reversing device-scope barrier. fp32 (no fp32 MFMA on CDNA4).
// De-templated everything: ROCm 7.2 clang ICE'd on dependent-size array refs.

constexpr int BSZ  = 64;
constexpr int LSEQ = 128;
constexpr int TENC = 256;
constexpr int CIN  = 256;
constexpr int HU   = 512;
constexpr int ODIM = 128;
constexpr int NBLK = 256;
constexpr int KBIG = 1 << 30;

struct Params {
  const float *x, *h_en, *W_dec, *W_enc, *b_enc, *w_score, *W_yattn, *b_yattn;
  const float *W_ih, *b_ih, *W_hh;
  const float *W_ff1, *b_ff1, *W_ff2, *b_ff2, *W_ta, *b_ta, *W_tb, *b_tb;
  const float *W_o1, *b_o1, *W_o2, *b_o2;
  float *out;
  float *pe;        // [B][TENC][HU] proj_enc
  float *pd_part;   // [8][B][HU] split-K partials of proj_dec
  float *e_buf;     // [B][TENC]
  float *ctx;       // [B][HU]
  float *xhat;      // [B][CIN]
  float *hlstm;     // [B][HU]
  float *h_buf;     // [B][HU]
  float *c_buf;     // [B][HU]
  float *hid;       // [B][HU]
  unsigned *bar;    // [2] count, generation (memset 0 pre-launch)
};

__device__ __forceinline__ float frcp_(float x) { return __builtin_amdgcn_rcpf(x); }
__device__ __forceinline__ float ftanh_(float x) {
  return 1.0f - 2.0f * frcp_(1.0f + __expf(2.0f * x));
}
__device__ __forceinline__ float fsig_(float x) {
  return frcp_(1.0f + __expf(-x));
}

// Sense-reversing grid barrier, device scope. All NBLK blocks co-resident.
__device__ __forceinline__ void gridbar(unsigned* bar) {
  __syncthreads();
  if (threadIdx.x == 0) {
    __threadfence();
    unsigned g = __hip_atomic_load(bar + 1, __ATOMIC_RELAXED, __HIP_MEMORY_SCOPE_AGENT);
    unsigned a = __hip_atomic_fetch_add(bar, 1u, __ATOMIC_ACQ_REL, __HIP_MEMORY_SCOPE_AGENT);
    if (a == (unsigned)NBLK - 1u) {
      __hip_atomic_store(bar, 0u, __ATOMIC_RELAXED, __HIP_MEMORY_SCOPE_AGENT);
      __hip_atomic_store(bar + 1, g + 1u, __ATOMIC_RELEASE, __HIP_MEMORY_SCOPE_AGENT);
    } else {
      while (__hip_atomic_load(bar + 1, __ATOMIC_ACQUIRE, __HIP_MEMORY_SCOPE_AGENT) == g)
        __builtin_amdgcn_s_sleep(1);
    }
  }
  __syncthreads();
}

// Stage one 64-wide K slice of A (arows x 64) and W (wrows x 64) into LDS.
// A element (r,k): k<splitA -> A0[r*lda0+k] else A1[r*lda1+(k-splitA)]
// W element (c,k): k<splitW -> wr0[c][k]    else wr1[c][k-splitW]
__device__ __forceinline__ void stage_slice(
    float (*As)[68], float (*Ws)[68], int arows, int wrows,
    const float* const* wr0, const float* const* wr1, int splitW,
    const float* A0, int lda0, const float* A1, int lda1, int splitA, int kb)
{
  const int t = threadIdx.x;
  for (int idx = t; idx < arows * 16; idx += 256) {
    int r = idx >> 4, kq = (idx & 15) << 2;
    int k = kb + kq;
    const float* src = (k < splitA) ? (A0 + r * lda0 + k) : (A1 + r * lda1 + (k - splitA));
    *(float4*)&As[r][kq] = *(const float4*)src;
  }
  for (int idx = t; idx < wrows * 16; idx += 256) {
    int c = idx >> 4, kq = (idx & 15) << 2;
    int k = kb + kq;
    const float* src = (k < splitW) ? (wr0[c] + k) : (wr1[c] + (k - splitW));
    *(float4*)&Ws[c][kq] = *(const float4*)src;
  }
}

// 64x16 output tile, 4 outputs/thread (2 rows x 2 cols).
__device__ __forceinline__ void gemm64x16(
    float (*As)[68], float (*Ws)[68],
    const float* const* wr0, const float* const* wr1, int splitW, const float* biasS,
    const float* A0, int lda0, const float* A1, int lda1, int splitA,
    int kbase, int klen, float (&acc)[2][2], int& b0o, int& c0o)
{
  const int t = threadIdx.x;
  const int c0 = (t & 7) * 2;
  const int b0 = (t >> 3) * 2;
  __syncthreads();  // tables written; previous-phase LDS readers done
  acc[0][0] = biasS[c0]; acc[0][1] = biasS[c0 + 1];
  acc[1][0] = biasS[c0]; acc[1][1] = biasS[c0 + 1];
  const int ns = klen >> 6;
  for (int s = 0; s < ns; ++s) {
    stage_slice(As, Ws, 64, 16, wr0, wr1, splitW, A0, lda0, A1, lda1, splitA, kbase + (s << 6));
    __syncthreads();
#pragma unroll
    for (int k4 = 0; k4 < 16; ++k4) {
      float4 w0 = *(float4*)&Ws[c0][k4 << 2];
      float4 w1 = *(float4*)&Ws[c0 + 1][k4 << 2];
#pragma unroll
      for (int i = 0; i < 2; ++i) {
        float4 a = *(float4*)&As[b0 + i][k4 << 2];
        acc[i][0] = fmaf(a.x, w0.x, acc[i][0]);
        acc[i][0] = fmaf(a.y, w0.y, acc[i][0]);
        acc[i][0] = fmaf(a.z, w0.z, acc[i][0]);
        acc[i][0] = fmaf(a.w, w0.w, acc[i][0]);
        acc[i][1] = fmaf(a.x, w1.x, acc[i][1]);
        acc[i][1] = fmaf(a.y, w1.y, acc[i][1]);
        acc[i][1] = fmaf(a.z, w1.z, acc[i][1]);
        acc[i][1] = fmaf(a.w, w1.w, acc[i][1]);
      }
    }
    __syncthreads();
  }
  b0o = b0; c0o = c0;
}

// 32x16 output tile, 2 outputs/thread (1 row x 2 cols).
__device__ __forceinline__ void gemm32x16(
    float (*As)[68], float (*Ws)[68],
    const float* const* wr0, const float* const* wr1, int splitW, const float* biasS,
    const float* A0, int lda0, const float* A1, int lda1, int splitA,
    int kbase, int klen, float (&acc)[2], int& b0o, int& c0o)
{
  const int t = threadIdx.x;
  const int c0 = (t & 7) * 2;
  const int b0 = t >> 3;
  __syncthreads();
  acc[0] = biasS[c0]; acc[1] = biasS[c0 + 1];
  const int ns = klen >> 6;
  for (int s = 0; s < ns; ++s) {
    stage_slice(As, Ws, 32, 16, wr0, wr1, splitW, A0, lda0, A1, lda1, splitA, kbase + (s << 6));
    __syncthreads();
#pragma unroll
    for (int k4 = 0; k4 < 16; ++k4) {
      float4 w0 = *(float4*)&Ws[c0][k4 << 2];
      float4 w1 = *(float4*)&Ws[c0 + 1][k4 << 2];
      float4 a  = *(float4*)&As[b0][k4 << 2];
      acc[0] = fmaf(a.x, w0.x, acc[0]);
      acc[0] = fmaf(a.y, w0.y, acc[0]);
      acc[0] = fmaf(a.z, w0.z, acc[0]);
      acc[0] = fmaf(a.w, w0.w, acc[0]);
      acc[1] = fmaf(a.x, w1.x, acc[1]);
      acc[1] = fmaf(a.y, w1.y, acc[1]);
      acc[1] = fmaf(a.z, w1.z, acc[1]);
      acc[1] = fmaf(a.w, w1.w, acc[1]);
    }
    __syncthreads();
  }
  b0o = b0; c0o = c0;
}

// 64x32 output tile, 8 outputs/thread (2 rows x 4 cols) — P0 only.
__device__ __forceinline__ void gemm64x32(
    float (*As)[68], float (*Ws)[68],
    const float* const* wr0, const float* biasS,
    const float* A0, int lda0, int klen, float (&acc)[2][4], int& b0o, int& c0o)
{
  const int t = threadIdx.x;
  const int c0 = (t & 7) * 4;
  const int b0 = (t >> 3) * 2;
  __syncthreads();
#pragma unroll
  for (int i = 0; i < 2; ++i)
#pragma unroll
    for (int j = 0; j < 4; ++j) acc[i][j] = biasS[c0 + j];
  const int ns = klen >> 6;
  for (int s = 0; s < ns; ++s) {
    stage_slice(As, Ws, 64, 32, wr0, wr0, KBIG, A0, lda0, A0, lda0, KBIG, s << 6);
    __syncthreads();
#pragma unroll
    for (int k4 = 0; k4 < 16; ++k4) {
      float4 w0 = *(float4*)&Ws[c0][k4 << 2];
      float4 w1 = *(float4*)&Ws[c0 + 1][k4 << 2];
      float4 w2 = *(float4*)&Ws[c0 + 2][k4 << 2];
      float4 w3 = *(float4*)&Ws[c0 + 3][k4 << 2];
#pragma unroll
      for (int i = 0; i < 2; ++i) {
        float4 a = *(float4*)&As[b0 + i][k4 << 2];
        acc[i][0] = fmaf(a.x, w0.x, acc[i][0]); acc[i][0] = fmaf(a.y, w0.y, acc[i][0]);
        acc[i][0] = fmaf(a.z, w0.z, acc[i][0]); acc[i][0] = fmaf(a.w, w0.w, acc[i][0]);
        acc[i][1] = fmaf(a.x, w1.x, acc[i][1]); acc[i][1] = fmaf(a.y, w1.y, acc[i][1]);
        acc[i][1] = fmaf(a.z, w1.z, acc[i][1]); acc[i][1] = fmaf(a.w, w1.w, acc[i][1]);
        acc[i][2] = fmaf(a.x, w2.x, acc[i][2]); acc[i][2] = fmaf(a.y, w2.y, acc[i][2]);
        acc[i][2] = fmaf(a.z, w2.z, acc[i][2]); acc[i][2] = fmaf(a.w, w2.w, acc[i][2]);
        acc[i][3] = fmaf(a.x, w3.x, acc[i][3]); acc[i][3] = fmaf(a.y, w3.y, acc[i][3]);
        acc[i][3] = fmaf(a.z, w3.z, acc[i][3]); acc[i][3] = fmaf(a.w, w3.w, acc[i][3]);
      }
    }
    __syncthreads();
  }
  b0o = b0; c0o = c0;
}

__launch_bounds__(256)
__global__ void cfc_kernel(Params P) {
  __shared__ float As[64][68];
  __shared__ float Ws[32][68];
  __shared__ const float* wr0[32];
  __shared__ const float* wr1[32];
  __shared__ float biasS[32];
  __shared__ float misc[1088];

  const int t = threadIdx.x;

  // ---------------- P0: proj_enc (16384 x 512, K=512) + zero h/c ----------------
  for (int job = blockIdx.x; job < 4096 + 32; job += NBLK) {
    if (job < 4096) {
      int rt = job >> 4, ct = job & 15;
      if (t < 32) {
        wr0[t] = P.W_enc + (ct * 32 + t) * HU;
        biasS[t] = P.b_enc[ct * 32 + t];
      }
      float acc[2][4]; int b0, c0;
      gemm64x32(As, Ws, wr0, biasS, P.h_en + rt * 64 * HU, HU, 512, acc, b0, c0);
      float* outp = P.pe + rt * 64 * HU + ct * 32;
#pragma unroll
      for (int i = 0; i < 2; ++i)
#pragma unroll
        for (int j = 0; j < 4; ++j)
          outp[(b0 + i) * HU + c0 + j] = acc[i][j];
    } else {
      int idx = job - 4096;
      float* base = (idx < 16 ? P.h_buf : P.c_buf) + (idx & 15) * 2048;
      for (int i = t; i < 512; i += 256)
        ((float4*)base)[i] = make_float4(0.f, 0.f, 0.f, 0.f);
    }
  }
  gridbar(P.bar);

  // ---------------- scan over 128 steps ----------------
  for (int step = 0; step < LSEQ; ++step) {
    const float* xt = P.x + step * CIN;  // row b -> + b*(LSEQ*CIN)

    // --- A: proj_dec partials. 256 jobs = 32 col-tiles x 8 K-splits.
    {
      int ut = blockIdx.x & 31, ks = blockIdx.x >> 5;
      if (t < 16) {
        wr0[t] = P.W_dec + (ut * 16 + t) * 1024;
        wr1[t] = wr0[t];
        biasS[t] = 0.f;
      }
      float acc[2][2]; int b0, c0;
      gemm64x16(As, Ws, wr0, wr1, KBIG, biasS,
                P.h_buf, HU, P.c_buf, HU, 512, ks * 128, 128, acc, b0, c0);
      float* outp = P.pd_part + ks * (BSZ * HU) + ut * 16;
      outp[b0 * HU + c0] = acc[0][0];
      outp[b0 * HU + c0 + 1] = acc[0][1];
      outp[(b0 + 1) * HU + c0] = acc[1][0];
      outp[(b0 + 1) * HU + c0 + 1] = acc[1][1];
    }
    gridbar(P.bar);

    // --- B1: attention logits e[b,t]. 256 jobs = 64 b x 4 t-quarters.
    {
      int b = blockIdx.x >> 2, tq = blockIdx.x & 3;
      float* pds = misc;        // [512]
      float* wsc = misc + 512;  // [512]
      __syncthreads();
      for (int h = t; h < HU; h += 256) {
        float s = 0.f;
#pragma unroll
        for (int p8 = 0; p8 < 8; ++p8) s += P.pd_part[p8 * (BSZ * HU) + b * HU + h];
        pds[h] = s;
        wsc[h] = P.w_score[h];
      }
      __syncthreads();
      int q = t & 3, tt = tq * 64 + (t >> 2);
      const float* per = P.pe + (b * TENC + tt) * HU + q * 128;
      float acc = 0.f;
      for (int h4 = 0; h4 < 32; ++h4) {
        float4 pv = *(const float4*)(per + h4 * 4);
        int hb = q * 128 + h4 * 4;
        acc += wsc[hb + 0] * ftanh_(pds[hb + 0] + pv.x);
        acc += wsc[hb + 1] * ftanh_(pds[hb + 1] + pv.y);
        acc += wsc[hb + 2] * ftanh_(pds[hb + 2] + pv.z);
        acc += wsc[hb + 3] * ftanh_(pds[hb + 3] + pv.w);
      }
      acc += __shfl_xor(acc, 1);
      acc += __shfl_xor(acc, 2);
      if (q == 0) P.e_buf[b * TENC + tt] = acc;
    }
    gridbar(P.bar);

    // --- B2: softmax (x4 redundant) + context slice. 64 b x 4 m-quarters.
    {
      int b = blockIdx.x >> 2, mq = blockIdx.x & 3;
      float* es = misc;          // [256]
      float* red = misc + 512;   // [8]
      float v = P.e_buf[b * TENC + t];
      float m = v;
#pragma unroll
      for (int o = 1; o < 64; o <<= 1) m = fmaxf(m, __shfl_xor(m, o));
      int wid = t >> 6;
      if ((t & 63) == 0) red[wid] = m;
      __syncthreads();
      m = fmaxf(fmaxf(red[0], red[1]), fmaxf(red[2], red[3]));
      float p = __expf(v - m);
      float s = p;
#pragma unroll
      for (int o = 1; o < 64; o <<= 1) s += __shfl_xor(s, o);
      if ((t & 63) == 0) red[4 + wid] = s;
      __syncthreads();
      float sum = (red[4] + red[5]) + (red[6] + red[7]);
      es[t] = p * frcp_(sum);
      __syncthreads();
      if (t < 128) {
        int mcol = mq * 128 + t;
        const float* hb = P.h_en + b * TENC * HU + mcol;
        float a0 = 0.f, a1 = 0.f, a2 = 0.f, a3 = 0.f;
        for (int tt = 0; tt < TENC; tt += 4) {
          a0 = fmaf(es[tt + 0], hb[(tt + 0) * HU], a0);
          a1 = fmaf(es[tt + 1], hb[(tt + 1) * HU], a1);
          a2 = fmaf(es[tt + 2], hb[(tt + 2) * HU], a2);
          a3 = fmaf(es[tt + 3], hb[(tt + 3) * HU], a3);
        }
        P.ctx[b * HU + mcol] = (a0 + a1) + (a2 + a3);
      }
    }
    gridbar(P.bar);

    // --- C: x_hat = [xt|ctx] @ W_yattn^T + b. 16 jobs (64x16, K=768).
    if (blockIdx.x < 16) {
      int ot = blockIdx.x;
      if (t < 16) {
        wr0[t] = P.W_yattn + (ot * 16 + t) * 768;
        wr1[t] = wr0[t];
        biasS[t] = P.b_yattn[ot * 16 + t];
      }
      float acc[2][2]; int b0, c0;
      gemm64x16(As, Ws, wr0, wr1, KBIG, biasS,
                xt, LSEQ * CIN, P.ctx, HU, 256, 0, 768, acc, b0, c0);
      float* outp = P.xhat + ot * 16;
      outp[b0 * CIN + c0] = acc[0][0];
      outp[b0 * CIN + c0 + 1] = acc[0][1];
      outp[(b0 + 1) * CIN + c0] = acc[1][0];
      outp[(b0 + 1) * CIN + c0 + 1] = acc[1][1];
    }
    gridbar(P.bar);

    // --- D: LSTM gates + elementwise. 256 jobs = 2 b-halves x 128 j-quads.
    {
      int bt = blockIdx.x & 1, jq = blockIdx.x >> 1;
      int j0 = jq * 4, rowbase = bt * 32;
      if (t < 16) {
        int jj = t >> 2, g = t & 3;
        int r = g * 512 + j0 + jj;
        wr0[t] = P.W_ih + r * 256;
        wr1[t] = P.W_hh + r * 512;
        biasS[t] = P.b_ih[r];
      }
      float acc[2]; int b0, c0;
      gemm32x16(As, Ws, wr0, wr1, 256, biasS,
                P.xhat + rowbase * CIN, CIN, P.h_buf + rowbase * HU, HU, 256,
                0, 768, acc, b0, c0);
      float* zs = misc;  // [32][16]
      zs[b0 * 16 + c0] = acc[0];
      zs[b0 * 16 + c0 + 1] = acc[1];
      __syncthreads();
      if (t < 128) {
        int b = t >> 2, jj = t & 3;
        int gb = rowbase + b, j = j0 + jj;
        float i_ = zs[b * 16 + jj * 4 + 0];
        float ig = zs[b * 16 + jj * 4 + 1];
        float fg = zs[b * 16 + jj * 4 + 2];
        float og = zs[b * 16 + jj * 4 + 3];
        float cold = P.c_buf[gb * HU + j];
        float cn = cold * fsig_(fg + 1.0f) + ftanh_(i_) * fsig_(ig);
        P.c_buf[gb * HU + j] = cn;
        P.hlstm[gb * HU + j] = ftanh_(cn) * fsig_(og);
      }
    }
    gridbar(P.bar);

    // --- E: CfC ff1/ff2/ta/tb + combine -> new h. 256 jobs like D.
    {
      int bt = blockIdx.x & 1, jq = blockIdx.x >> 1;
      int j0 = jq * 4, rowbase = bt * 32;
      if (t < 16) {
        int jj = t >> 2, m = t & 3;
        const float* Wm = (m == 0) ? P.W_ff1 : (m == 1) ? P.W_ff2 : (m == 2) ? P.W_ta : P.W_tb;
        const float* bm = (m == 0) ? P.b_ff1 : (m == 1) ? P.b_ff2 : (m == 2) ? P.b_ta : P.b_tb;
        wr0[t] = Wm + (j0 + jj) * 768;
        wr1[t] = wr0[t];
        biasS[t] = bm[j0 + jj];
      }
      float acc[2]; int b0, c0;
      gemm32x16(As, Ws, wr0, wr1, KBIG, biasS,
                P.xhat + rowbase * CIN, CIN, P.hlstm + rowbase * HU, HU, 256,
                0, 768, acc, b0, c0);
      float* es2 = misc;  // [32][16]
      es2[b0 * 16 + c0] = acc[0];
      es2[b0 * 16 + c0 + 1] = acc[1];
      __syncthreads();
      if (t < 128) {
        int b = t >> 2, jj = t & 3;
        int gb = rowbase + b, j = j0 + jj;
        float ff1 = ftanh_(es2[b * 16 + jj * 4 + 0]);
        float ff2 = ftanh_(es2[b * 16 + jj * 4 + 1]);
        float ta  = es2[b * 16 + jj * 4 + 2];
        float tb  = es2[b * 16 + jj * 4 + 3];
        float ti = fsig_(ta + tb);  // ts = 1.0
        P.h_buf[gb * HU + j] = ff1 * (1.0f - ti) + ti * ff2;
      }
    }
    gridbar(P.bar);
  }

  // ---------------- F1: hid = leaky_relu([h|c_last(ctx)] @ W_o1^T + b). 32 jobs ----------------
  if (blockIdx.x < 32) {
    int ut = blockIdx.x;
    if (t < 16) {
      wr0[t] = P.W_o1 + (ut * 16 + t) * 1024;
      wr1[t] = wr0[t];
      biasS[t] = P.b_o1[ut * 16 + t];
    }
    float acc[2][2]; int b0, c0;
    // NOTE: reference's c_last is the final attention CONTEXT, not the cell state.
    gemm64x16(As, Ws, wr0, wr1, KBIG, biasS,
              P.h_buf, HU, P.ctx, HU, 512, 0, 1024, acc, b0, c0);
    float* outp = P.hid + ut * 16;
#pragma unroll
    for (int i = 0; i < 2; ++i)
#pragma unroll
      for (int j = 0; j < 2; ++j) {
        float v = acc[i][j];
        outp[(b0 + i) * HU + c0 + j] = v > 0.f ? v : 0.01f * v;
      }
  }
  gridbar(P.bar);

  // ---------------- F2: out = hid @ W_o2^T + b (8 jobs) + state copies ----------------
  {
    int job = blockIdx.x;
    if (job < 8) {
      if (t < 16) {
        wr0[t] = P.W_o2 + (job * 16 + t) * HU;
        wr1[t] = wr0[t];
        biasS[t] = P.b_o2[job * 16 + t];
      }
      float acc[2][2]; int b0, c0;
      gemm64x16(As, Ws, wr0, wr1, KBIG, biasS,
                P.hid, HU, P.hid, HU, KBIG, 0, 512, acc, b0, c0);
      float* outp = P.out + job * 16;
      outp[b0 * ODIM + c0] = acc[0][0];
      outp[b0 * ODIM + c0 + 1] = acc[0][1];
      outp[(b0 + 1) * ODIM + c0] = acc[1][0];
      outp[(b0 + 1) * ODIM + c0 + 1] = acc[1][1];
    } else if (job < 40) {
      int idx = job - 8;
      const float* src = (idx < 16 ? P.h_buf : P.c_buf) + (idx & 15) * 2048;
      float* dst = P.out + BSZ * ODIM + (idx < 16 ? 0 : BSZ * HU) + (idx & 15) * 2048;
      for (int i = t; i < 512; i += 256)
        ((float4*)dst)[i] = ((const float4*)src)[i];
    }
  }
}

extern "C" void kernel_launch(void* const* d_in, const int* in_sizes, int n_in,
                              void* d_out, int out_size, void* d_ws, size_t ws_size,
                              hipStream_t stream) {
  (void)in_sizes; (void)n_in; (void)out_size; (void)ws_size;
  Params P;
  P.x       = (const float*)d_in[0];
  P.h_en    = (const float*)d_in[1];
  P.W_dec   = (const float*)d_in[2];
  P.W_enc   = (const float*)d_in[3];
  P.b_enc   = (const float*)d_in[4];
  P.w_score = (const float*)d_in[5];
  P.W_yattn = (const float*)d_in[6];
  P.b_yattn = (const float*)d_in[7];
  P.W_ih    = (const float*)d_in[8];
  P.b_ih    = (const float*)d_in[9];
  P.W_hh    = (const float*)d_in[10];
  P.W_ff1   = (const float*)d_in[11];
  P.b_ff1   = (const float*)d_in[12];
  P.W_ff2   = (const float*)d_in[13];
  P.b_ff2   = (const float*)d_in[14];
  P.W_ta    = (const float*)d_in[15];
  P.b_ta    = (const float*)d_in[16];
  P.W_tb    = (const float*)d_in[17];
  P.b_tb    = (const float*)d_in[18];
  P.W_o1    = (const float*)d_in[19];
  P.b_o1    = (const float*)d_in[20];
  P.W_o2    = (const float*)d_in[21];
  P.b_o2    = (const float*)d_in[22];
  P.out     = (float*)d_out;

  float* ws = (float*)d_ws;
  size_t off = 0;
  P.pe      = ws + off; off += (size_t)BSZ * TENC * HU;  // 8,388,608 floats
  P.pd_part = ws + off; off += (size_t)8 * BSZ * HU;
  P.e_buf   = ws + off; off += (size_t)BSZ * TENC;
  P.ctx     = ws + off; off += (size_t)BSZ * HU;
  P.xhat    = ws + off; off += (size_t)BSZ * CIN;
  P.hlstm   = ws + off; off += (size_t)BSZ * HU;
  P.h_buf   = ws + off; off += (size_t)BSZ * HU;
  P.c_buf   = ws + off; off += (size_t)BSZ * HU;
  P.hid     = ws + off; off += (size_t)BSZ * HU;
  P.bar     = (unsigned*)(ws + off);

  // ws (incl. barrier words) is poisoned 0xAA before every launch.
  hipMemsetAsync((void*)P.bar, 0, 64, stream);

  hipLaunchKernelGGL(cfc_kernel, dim3(NBLK), dim3(256), 0, stream, P);
}

// Round 4
// 43941.550 us; speedup vs baseline: 1.0482x; 1.0482x over previous
//
#include <hip/hip_runtime.h>

// CfC decoder on MI355X: one persistent kernel (256 blocks x 256 threads, all
// co-resident) runs the whole 128-step scan; grid-wide phases separated by a
// flag-array grid barrier (no atomic RMW storm: one release STORE per block,
// master block gathers, publishes a generation word everyone polls).
// fp32 (no fp32 MFMA on CDNA4).

constexpr int BSZ  = 64;
constexpr int LSEQ = 128;
constexpr int TENC = 256;
constexpr int CIN  = 256;
constexpr int HU   = 512;
constexpr int ODIM = 128;
constexpr int NBLK = 256;
constexpr int KBIG = 1 << 30;

struct Params {
  const float *x, *h_en, *W_dec, *W_enc, *b_enc, *w_score, *W_yattn, *b_yattn;
  const float *W_ih, *b_ih, *W_hh;
  const float *W_ff1, *b_ff1, *W_ff2, *b_ff2, *W_ta, *b_ta, *W_tb, *b_tb;
  const float *W_o1, *b_o1, *W_o2, *b_o2;
  float *out;
  float *pe;        // [B][TENC][HU] proj_enc
  float *pd_part;   // [8][B][HU] split-K partials of proj_dec
  float *e_buf;     // [B][TENC]
  float *ctx;       // [B][HU]
  float *xhat;      // [B][CIN]
  float *hlstm;     // [B][HU]
  float *h_buf;     // [B][HU]
  float *c_buf;     // [B][HU]
  float *hid;       // [B][HU]
  unsigned *bar;    // [16] generation word (own cacheline), memset 0 pre-launch
  unsigned *flags;  // [256*16] per-block arrival flags, 64B stride, memset 0
};

__device__ __forceinline__ float frcp_(float x) { return __builtin_amdgcn_rcpf(x); }
__device__ __forceinline__ float ftanh_(float x) {
  return 1.0f - 2.0f * frcp_(1.0f + __expf(2.0f * x));
}
__device__ __forceinline__ float fsig_(float x) {
  return frcp_(1.0f + __expf(-x));
}

// Flag-array grid barrier. Each block: one release store to its own 64B slot.
// Block 0: 256 threads poll the 256 slots in parallel, then thread 0 publishes
// bar[0] = gen. All blocks spin on bar[0] with acquire loads (read-only
// polling, no ownership transfer). gen increases monotonically; all blocks
// execute the same barrier sequence.
__device__ __forceinline__ void gridbar(unsigned* bar, unsigned* flags, unsigned gen) {
  __syncthreads();
  const int t = threadIdx.x;
  if (t == 0) {
    __hip_atomic_store(flags + blockIdx.x * 16, gen,
                       __ATOMIC_RELEASE, __HIP_MEMORY_SCOPE_AGENT);
  }
  if (blockIdx.x == 0) {
    while (__hip_atomic_load(flags + t * 16, __ATOMIC_ACQUIRE,
                             __HIP_MEMORY_SCOPE_AGENT) < gen)
      __builtin_amdgcn_s_sleep(1);
    __syncthreads();
    if (t == 0)
      __hip_atomic_store(bar, gen, __ATOMIC_RELEASE, __HIP_MEMORY_SCOPE_AGENT);
  }
  if (t == 0) {
    while (__hip_atomic_load(bar, __ATOMIC_ACQUIRE,
                             __HIP_MEMORY_SCOPE_AGENT) < gen)
      __builtin_amdgcn_s_sleep(1);
  }
  __syncthreads();
}

// Stage one 64-wide K slice of A (arows x 64) and W (wrows x 64) into LDS.
__device__ __forceinline__ void stage_slice(
    float (*As)[68], float (*Ws)[68], int arows, int wrows,
    const float* const* wr0, const float* const* wr1, int splitW,
    const float* A0, int lda0, const float* A1, int lda1, int splitA, int kb)
{
  const int t = threadIdx.x;
  for (int idx = t; idx < arows * 16; idx += 256) {
    int r = idx >> 4, kq = (idx & 15) << 2;
    int k = kb + kq;
    const float* src = (k < splitA) ? (A0 + r * lda0 + k) : (A1 + r * lda1 + (k - splitA));
    *(float4*)&As[r][kq] = *(const float4*)src;
  }
  for (int idx = t; idx < wrows * 16; idx += 256) {
    int c = idx >> 4, kq = (idx & 15) << 2;
    int k = kb + kq;
    const float* src = (k < splitW) ? (wr0[c] + k) : (wr1[c] + (k - splitW));
    *(float4*)&Ws[c][kq] = *(const float4*)src;
  }
}

// 64x16 output tile, 4 outputs/thread (2 rows x 2 cols).
__device__ __forceinline__ void gemm64x16(
    float (*As)[68], float (*Ws)[68],
    const float* const* wr0, const float* const* wr1, int splitW, const float* biasS,
    const float* A0, int lda0, const float* A1, int lda1, int splitA,
    int kbase, int klen, float (&acc)[2][2], int& b0o, int& c0o)
{
  const int t = threadIdx.x;
  const int c0 = (t & 7) * 2;
  const int b0 = (t >> 3) * 2;
  __syncthreads();  // tables written; previous-phase LDS readers done
  acc[0][0] = biasS[c0]; acc[0][1] = biasS[c0 + 1];
  acc[1][0] = biasS[c0]; acc[1][1] = biasS[c0 + 1];
  const int ns = klen >> 6;
  for (int s = 0; s < ns; ++s) {
    stage_slice(As, Ws, 64, 16, wr0, wr1, splitW, A0, lda0, A1, lda1, splitA, kbase + (s << 6));
    __syncthreads();
#pragma unroll
    for (int k4 = 0; k4 < 16; ++k4) {
      float4 w0 = *(float4*)&Ws[c0][k4 << 2];
      float4 w1 = *(float4*)&Ws[c0 + 1][k4 << 2];
#pragma unroll
      for (int i = 0; i < 2; ++i) {
        float4 a = *(float4*)&As[b0 + i][k4 << 2];
        acc[i][0] = fmaf(a.x, w0.x, acc[i][0]);
        acc[i][0] = fmaf(a.y, w0.y, acc[i][0]);
        acc[i][0] = fmaf(a.z, w0.z, acc[i][0]);
        acc[i][0] = fmaf(a.w, w0.w, acc[i][0]);
        acc[i][1] = fmaf(a.x, w1.x, acc[i][1]);
        acc[i][1] = fmaf(a.y, w1.y, acc[i][1]);
        acc[i][1] = fmaf(a.z, w1.z, acc[i][1]);
        acc[i][1] = fmaf(a.w, w1.w, acc[i][1]);
      }
    }
    __syncthreads();
  }
  b0o = b0; c0o = c0;
}

// 32x16 output tile, 2 outputs/thread (1 row x 2 cols).
__device__ __forceinline__ void gemm32x16(
    float (*As)[68], float (*Ws)[68],
    const float* const* wr0, const float* const* wr1, int splitW, const float* biasS,
    const float* A0, int lda0, const float* A1, int lda1, int splitA,
    int kbase, int klen, float (&acc)[2], int& b0o, int& c0o)
{
  const int t = threadIdx.x;
  const int c0 = (t & 7) * 2;
  const int b0 = t >> 3;
  __syncthreads();
  acc[0] = biasS[c0]; acc[1] = biasS[c0 + 1];
  const int ns = klen >> 6;
  for (int s = 0; s < ns; ++s) {
    stage_slice(As, Ws, 32, 16, wr0, wr1, splitW, A0, lda0, A1, lda1, splitA, kbase + (s << 6));
    __syncthreads();
#pragma unroll
    for (int k4 = 0; k4 < 16; ++k4) {
      float4 w0 = *(float4*)&Ws[c0][k4 << 2];
      float4 w1 = *(float4*)&Ws[c0 + 1][k4 << 2];
      float4 a  = *(float4*)&As[b0][k4 << 2];
      acc[0] = fmaf(a.x, w0.x, acc[0]);
      acc[0] = fmaf(a.y, w0.y, acc[0]);
      acc[0] = fmaf(a.z, w0.z, acc[0]);
      acc[0] = fmaf(a.w, w0.w, acc[0]);
      acc[1] = fmaf(a.x, w1.x, acc[1]);
      acc[1] = fmaf(a.y, w1.y, acc[1]);
      acc[1] = fmaf(a.z, w1.z, acc[1]);
      acc[1] = fmaf(a.w, w1.w, acc[1]);
    }
    __syncthreads();
  }
  b0o = b0; c0o = c0;
}

// 64x32 output tile, 8 outputs/thread (2 rows x 4 cols) — P0 only.
__device__ __forceinline__ void gemm64x32(
    float (*As)[68], float (*Ws)[68],
    const float* const* wr0, const float* biasS,
    const float* A0, int lda0, int klen, float (&acc)[2][4], int& b0o, int& c0o)
{
  const int t = threadIdx.x;
  const int c0 = (t & 7) * 4;
  const int b0 = (t >> 3) * 2;
  __syncthreads();
#pragma unroll
  for (int i = 0; i < 2; ++i)
#pragma unroll
    for (int j = 0; j < 4; ++j) acc[i][j] = biasS[c0 + j];
  const int ns = klen >> 6;
  for (int s = 0; s < ns; ++s) {
    stage_slice(As, Ws, 64, 32, wr0, wr0, KBIG, A0, lda0, A0, lda0, KBIG, s << 6);
    __syncthreads();
#pragma unroll
    for (int k4 = 0; k4 < 16; ++k4) {
      float4 w0 = *(float4*)&Ws[c0][k4 << 2];
      float4 w1 = *(float4*)&Ws[c0 + 1][k4 << 2];
      float4 w2 = *(float4*)&Ws[c0 + 2][k4 << 2];
      float4 w3 = *(float4*)&Ws[c0 + 3][k4 << 2];
#pragma unroll
      for (int i = 0; i < 2; ++i) {
        float4 a = *(float4*)&As[b0 + i][k4 << 2];
        acc[i][0] = fmaf(a.x, w0.x, acc[i][0]); acc[i][0] = fmaf(a.y, w0.y, acc[i][0]);
        acc[i][0] = fmaf(a.z, w0.z, acc[i][0]); acc[i][0] = fmaf(a.w, w0.w, acc[i][0]);
        acc[i][1] = fmaf(a.x, w1.x, acc[i][1]); acc[i][1] = fmaf(a.y, w1.y, acc[i][1]);
        acc[i][1] = fmaf(a.z, w1.z, acc[i][1]); acc[i][1] = fmaf(a.w, w1.w, acc[i][1]);
        acc[i][2] = fmaf(a.x, w2.x, acc[i][2]); acc[i][2] = fmaf(a.y, w2.y, acc[i][2]);
        acc[i][2] = fmaf(a.z, w2.z, acc[i][2]); acc[i][2] = fmaf(a.w, w2.w, acc[i][2]);
        acc[i][3] = fmaf(a.x, w3.x, acc[i][3]); acc[i][3] = fmaf(a.y, w3.y, acc[i][3]);
        acc[i][3] = fmaf(a.z, w3.z, acc[i][3]); acc[i][3] = fmaf(a.w, w3.w, acc[i][3]);
      }
    }
    __syncthreads();
  }
  b0o = b0; c0o = c0;
}

__launch_bounds__(256)
__global__ void cfc_kernel(Params P) {
  __shared__ float As[64][68];
  __shared__ float Ws[32][68];
  __shared__ const float* wr0[32];
  __shared__ const float* wr1[32];
  __shared__ float biasS[32];
  __shared__ float misc[1088];

  const int t = threadIdx.x;
  unsigned gen = 1;

  // ---------------- P0: proj_enc (16384 x 512, K=512) + zero h/c ----------------
  for (int job = blockIdx.x; job < 4096 + 32; job += NBLK) {
    if (job < 4096) {
      int rt = job >> 4, ct = job & 15;
      if (t < 32) {
        wr0[t] = P.W_enc + (ct * 32 + t) * HU;
        biasS[t] = P.b_enc[ct * 32 + t];
      }
      float acc[2][4]; int b0, c0;
      gemm64x32(As, Ws, wr0, biasS, P.h_en + rt * 64 * HU, HU, 512, acc, b0, c0);
      float* outp = P.pe + rt * 64 * HU + ct * 32;
#pragma unroll
      for (int i = 0; i < 2; ++i)
#pragma unroll
        for (int j = 0; j < 4; ++j)
          outp[(b0 + i) * HU + c0 + j] = acc[i][j];
    } else {
      int idx = job - 4096;
      float* base = (idx < 16 ? P.h_buf : P.c_buf) + (idx & 15) * 2048;
      for (int i = t; i < 512; i += 256)
        ((float4*)base)[i] = make_float4(0.f, 0.f, 0.f, 0.f);
    }
  }
  gridbar(P.bar, P.flags, gen++);

  // ---------------- scan over 128 steps ----------------
  for (int step = 0; step < LSEQ; ++step) {
    const float* xt = P.x + step * CIN;  // row b -> + b*(LSEQ*CIN)

    // --- A: proj_dec partials. 256 jobs = 32 col-tiles x 8 K-splits.
    {
      int ut = blockIdx.x & 31, ks = blockIdx.x >> 5;
      if (t < 16) {
        wr0[t] = P.W_dec + (ut * 16 + t) * 1024;
        wr1[t] = wr0[t];
        biasS[t] = 0.f;
      }
      float acc[2][2]; int b0, c0;
      gemm64x16(As, Ws, wr0, wr1, KBIG, biasS,
                P.h_buf, HU, P.c_buf, HU, 512, ks * 128, 128, acc, b0, c0);
      float* outp = P.pd_part + ks * (BSZ * HU) + ut * 16;
      outp[b0 * HU + c0] = acc[0][0];
      outp[b0 * HU + c0 + 1] = acc[0][1];
      outp[(b0 + 1) * HU + c0] = acc[1][0];
      outp[(b0 + 1) * HU + c0 + 1] = acc[1][1];
    }
    gridbar(P.bar, P.flags, gen++);

    // --- B1: attention logits e[b,t]. 256 jobs = 64 b x 4 t-quarters.
    // pds/wsc stored skewed (idx = h + (h>>7)) so the four q-groups hit
    // four different banks instead of all landing on bank 0 (128 % 32 == 0).
    {
      int b = blockIdx.x >> 2, tq = blockIdx.x & 3;
      float* pds = misc;        // [516] skewed
      float* wsc = misc + 520;  // [516] skewed
      __syncthreads();
      for (int h = t; h < HU; h += 256) {
        float s = 0.f;
#pragma unroll
        for (int p8 = 0; p8 < 8; ++p8) s += P.pd_part[p8 * (BSZ * HU) + b * HU + h];
        int hs = h + (h >> 7);
        pds[hs] = s;
        wsc[hs] = P.w_score[h];
      }
      __syncthreads();
      int q = t & 3, tt = tq * 64 + (t >> 2);
      const float* per = P.pe + (b * TENC + tt) * HU + q * 128;
      float acc = 0.f;
      for (int h4 = 0; h4 < 32; ++h4) {
        float4 pv = *(const float4*)(per + h4 * 4);
        int hbs = q * 129 + h4 * 4;  // skewed index of q*128 + h4*4
        acc += wsc[hbs + 0] * ftanh_(pds[hbs + 0] + pv.x);
        acc += wsc[hbs + 1] * ftanh_(pds[hbs + 1] + pv.y);
        acc += wsc[hbs + 2] * ftanh_(pds[hbs + 2] + pv.z);
        acc += wsc[hbs + 3] * ftanh_(pds[hbs + 3] + pv.w);
      }
      acc += __shfl_xor(acc, 1);
      acc += __shfl_xor(acc, 2);
      if (q == 0) P.e_buf[b * TENC + tt] = acc;
    }
    gridbar(P.bar, P.flags, gen++);

    // --- B2: softmax (x4 redundant) + context slice. 64 b x 4 m-quarters.
    {
      int b = blockIdx.x >> 2, mq = blockIdx.x & 3;
      float* es = misc;          // [256]
      float* red = misc + 512;   // [8]
      float v = P.e_buf[b * TENC + t];
      float m = v;
#pragma unroll
      for (int o = 1; o < 64; o <<= 1) m = fmaxf(m, __shfl_xor(m, o));
      int wid = t >> 6;
      if ((t & 63) == 0) red[wid] = m;
      __syncthreads();
      m = fmaxf(fmaxf(red[0], red[1]), fmaxf(red[2], red[3]));
      float p = __expf(v - m);
      float s = p;
#pragma unroll
      for (int o = 1; o < 64; o <<= 1) s += __shfl_xor(s, o);
      if ((t & 63) == 0) red[4 + wid] = s;
      __syncthreads();
      float sum = (red[4] + red[5]) + (red[6] + red[7]);
      es[t] = p * frcp_(sum);
      __syncthreads();
      if (t < 128) {
        int mcol = mq * 128 + t;
        const float* hb = P.h_en + b * TENC * HU + mcol;
        float a0 = 0.f, a1 = 0.f, a2 = 0.f, a3 = 0.f;
        for (int tt = 0; tt < TENC; tt += 4) {
          a0 = fmaf(es[tt + 0], hb[(tt + 0) * HU], a0);
          a1 = fmaf(es[tt + 1], hb[(tt + 1) * HU], a1);
          a2 = fmaf(es[tt + 2], hb[(tt + 2) * HU], a2);
          a3 = fmaf(es[tt + 3], hb[(tt + 3) * HU], a3);
        }
        P.ctx[b * HU + mcol] = (a0 + a1) + (a2 + a3);
      }
    }
    gridbar(P.bar, P.flags, gen++);

    // --- C: x_hat = [xt|ctx] @ W_yattn^T + b. 16 jobs (64x16, K=768).
    if (blockIdx.x < 16) {
      int ot = blockIdx.x;
      if (t < 16) {
        wr0[t] = P.W_yattn + (ot * 16 + t) * 768;
        wr1[t] = wr0[t];
        biasS[t] = P.b_yattn[ot * 16 + t];
      }
      float acc[2][2]; int b0, c0;
      gemm64x16(As, Ws, wr0, wr1, KBIG, biasS,
                xt, LSEQ * CIN, P.ctx, HU, 256, 0, 768, acc, b0, c0);
      float* outp = P.xhat + ot * 16;
      outp[b0 * CIN + c0] = acc[0][0];
      outp[b0 * CIN + c0 + 1] = acc[0][1];
      outp[(b0 + 1) * CIN + c0] = acc[1][0];
      outp[(b0 + 1) * CIN + c0 + 1] = acc[1][1];
    }
    gridbar(P.bar, P.flags, gen++);

    // --- D: LSTM gates + elementwise. 256 jobs = 2 b-halves x 128 j-quads.
    {
      int bt = blockIdx.x & 1, jq = blockIdx.x >> 1;
      int j0 = jq * 4, rowbase = bt * 32;
      if (t < 16) {
        int jj = t >> 2, g = t & 3;
        int r = g * 512 + j0 + jj;
        wr0[t] = P.W_ih + r * 256;
        wr1[t] = P.W_hh + r * 512;
        biasS[t] = P.b_ih[r];
      }
      float acc[2]; int b0, c0;
      gemm32x16(As, Ws, wr0, wr1, 256, biasS,
                P.xhat + rowbase * CIN, CIN, P.h_buf + rowbase * HU, HU, 256,
                0, 768, acc, b0, c0);
      float* zs = misc;  // [32][16]
      zs[b0 * 16 + c0] = acc[0];
      zs[b0 * 16 + c0 + 1] = acc[1];
      __syncthreads();
      if (t < 128) {
        int b = t >> 2, jj = t & 3;
        int gb = rowbase + b, j = j0 + jj;
        float i_ = zs[b * 16 + jj * 4 + 0];
        float ig = zs[b * 16 + jj * 4 + 1];
        float fg = zs[b * 16 + jj * 4 + 2];
        float og = zs[b * 16 + jj * 4 + 3];
        float cold = P.c_buf[gb * HU + j];
        float cn = cold * fsig_(fg + 1.0f) + ftanh_(i_) * fsig_(ig);
        P.c_buf[gb * HU + j] = cn;
        P.hlstm[gb * HU + j] = ftanh_(cn) * fsig_(og);
      }
    }
    gridbar(P.bar, P.flags, gen++);

    // --- E: CfC ff1/ff2/ta/tb + combine -> new h. 256 jobs like D.
    {
      int bt = blockIdx.x & 1, jq = blockIdx.x >> 1;
      int j0 = jq * 4, rowbase = bt * 32;
      if (t < 16) {
        int jj = t >> 2, m = t & 3;
        const float* Wm = (m == 0) ? P.W_ff1 : (m == 1) ? P.W_ff2 : (m == 2) ? P.W_ta : P.W_tb;
        const float* bm = (m == 0) ? P.b_ff1 : (m == 1) ? P.b_ff2 : (m == 2) ? P.b_ta : P.b_tb;
        wr0[t] = Wm + (j0 + jj) * 768;
        wr1[t] = wr0[t];
        biasS[t] = bm[j0 + jj];
      }
      float acc[2]; int b0, c0;
      gemm32x16(As, Ws, wr0, wr1, KBIG, biasS,
                P.xhat + rowbase * CIN, CIN, P.hlstm + rowbase * HU, HU, 256,
                0, 768, acc, b0, c0);
      float* es2 = misc;  // [32][16]
      es2[b0 * 16 + c0] = acc[0];
      es2[b0 * 16 + c0 + 1] = acc[1];
      __syncthreads();
      if (t < 128) {
        int b = t >> 2, jj = t & 3;
        int gb = rowbase + b, j = j0 + jj;
        float ff1 = ftanh_(es2[b * 16 + jj * 4 + 0]);
        float ff2 = ftanh_(es2[b * 16 + jj * 4 + 1]);
        float ta  = es2[b * 16 + jj * 4 + 2];
        float tb  = es2[b * 16 + jj * 4 + 3];
        float ti = fsig_(ta + tb);  // ts = 1.0
        P.h_buf[gb * HU + j] = ff1 * (1.0f - ti) + ti * ff2;
      }
    }
    gridbar(P.bar, P.flags, gen++);
  }

  // ---------------- F1: hid = leaky_relu([h|c_last(ctx)] @ W_o1^T + b). 32 jobs ----------------
  if (blockIdx.x < 32) {
    int ut = blockIdx.x;
    if (t < 16) {
      wr0[t] = P.W_o1 + (ut * 16 + t) * 1024;
      wr1[t] = wr0[t];
      biasS[t] = P.b_o1[ut * 16 + t];
    }
    float acc[2][2]; int b0, c0;
    // reference's c_last is the final attention CONTEXT, not the cell state.
    gemm64x16(As, Ws, wr0, wr1, KBIG, biasS,
              P.h_buf, HU, P.ctx, HU, 512, 0, 1024, acc, b0, c0);
    float* outp = P.hid + ut * 16;
#pragma unroll
    for (int i = 0; i < 2; ++i)
#pragma unroll
      for (int j = 0; j < 2; ++j) {
        float v = acc[i][j];
        outp[(b0 + i) * HU + c0 + j] = v > 0.f ? v : 0.01f * v;
      }
  }
  gridbar(P.bar, P.flags, gen++);

  // ---------------- F2: out = hid @ W_o2^T + b (8 jobs) + state copies ----------------
  {
    int job = blockIdx.x;
    if (job < 8) {
      if (t < 16) {
        wr0[t] = P.W_o2 + (job * 16 + t) * HU;
        wr1[t] = wr0[t];
        biasS[t] = P.b_o2[job * 16 + t];
      }
      float acc[2][2]; int b0, c0;
      gemm64x16(As, Ws, wr0, wr1, KBIG, biasS,
                P.hid, HU, P.hid, HU, KBIG, 0, 512, acc, b0, c0);
      float* outp = P.out + job * 16;
      outp[b0 * ODIM + c0] = acc[0][0];
      outp[b0 * ODIM + c0 + 1] = acc[0][1];
      outp[(b0 + 1) * ODIM + c0] = acc[1][0];
      outp[(b0 + 1) * ODIM + c0 + 1] = acc[1][1];
    } else if (job < 40) {
      int idx = job - 8;
      const float* src = (idx < 16 ? P.h_buf : P.c_buf) + (idx & 15) * 2048;
      float* dst = P.out + BSZ * ODIM + (idx < 16 ? 0 : BSZ * HU) + (idx & 15) * 2048;
      for (int i = t; i < 512; i += 256)
        ((float4*)dst)[i] = ((const float4*)src)[i];
    }
  }
}

extern "C" void kernel_launch(void* const* d_in, const int* in_sizes, int n_in,
                              void* d_out, int out_size, void* d_ws, size_t ws_size,
                              hipStream_t stream) {
  (void)in_sizes; (void)n_in; (void)out_size; (void)ws_size;
  Params P;
  P.x       = (const float*)d_in[0];
  P.h_en    = (const float*)d_in[1];
  P.W_dec   = (const float*)d_in[2];
  P.W_enc   = (const float*)d_in[3];
  P.b_enc   = (const float*)d_in[4];
  P.w_score = (const float*)d_in[5];
  P.W_yattn = (const float*)d_in[6];
  P.b_yattn = (const float*)d_in[7];
  P.W_ih    = (const float*)d_in[8];
  P.b_ih    = (const float*)d_in[9];
  P.W_hh    = (const float*)d_in[10];
  P.W_ff1   = (const float*)d_in[11];
  P.b_ff1   = (const float*)d_in[12];
  P.W_ff2   = (const float*)d_in[13];
  P.b_ff2   = (const float*)d_in[14];
  P.W_ta    = (const float*)d_in[15];
  P.b_ta    = (const float*)d_in[16];
  P.W_tb    = (const float*)d_in[17];
  P.b_tb    = (const float*)d_in[18];
  P.W_o1    = (const float*)d_in[19];
  P.b_o1    = (const float*)d_in[20];
  P.W_o2    = (const float*)d_in[21];
  P.b_o2    = (const float*)d_in[22];
  P.out     = (float*)d_out;

  float* ws = (float*)d_ws;
  size_t off = 0;
  P.pe      = ws + off; off += (size_t)BSZ * TENC * HU;  // 8,388,608 floats
  P.pd_part = ws + off; off += (size_t)8 * BSZ * HU;
  P.e_buf   = ws + off; off += (size_t)BSZ * TENC;
  P.ctx     = ws + off; off += (size_t)BSZ * HU;
  P.xhat    = ws + off; off += (size_t)BSZ * CIN;
  P.hlstm   = ws + off; off += (size_t)BSZ * HU;
  P.h_buf   = ws + off; off += (size_t)BSZ * HU;
  P.c_buf   = ws + off; off += (size_t)BSZ * HU;
  P.hid     = ws + off; off += (size_t)BSZ * HU;
  P.bar     = (unsigned*)(ws + off); off += 16;          // 64B line for gen word
  P.flags   = (unsigned*)(ws + off);                     // 256 x 64B flag slots

  // ws is poisoned 0xAA before every launch: zero barrier gen + flags.
  (void)hipMemsetAsync((void*)P.bar, 0, 64 + 256 * 64, stream);

  hipLaunchKernelGGL(cfc_kernel, dim3(NBLK), dim3(256), 0, stream, P);
}

// Round 5
// 17953.009 us; speedup vs baseline: 2.5656x; 2.4476x over previous
//
#include <hip/hip_runtime.h>

// CfC decoder on MI355X: persistent kernel, 256 blocks x 256 threads (1/CU),
// 128-step scan with grid-wide phases.
// KEY FIX vs r2/r4: no agent-scope ACQUIRE polling (each acquire emits
// buffer_inv -> nukes the per-XCD L2 every ~300ns, defeating all caching).
// Now: RELAXED (sc1) polling + all cross-block activations via relaxed agent
// atomics (bypass L2, MALL-coherent). Weights/x/h_en/pe stay L2-cached.
// fp32 throughout (no fp32 MFMA on CDNA4).

constexpr int BSZ  = 64;
constexpr int LSEQ = 128;
constexpr int TENC = 256;
constexpr int CIN  = 256;
constexpr int HU   = 512;
constexpr int ODIM = 128;
constexpr int NBLK = 256;
constexpr int KBIG = 1 << 30;

typedef unsigned long long ull;

struct Params {
  const float *x, *h_en, *W_dec, *W_enc, *b_enc, *w_score, *W_yattn, *b_yattn;
  const float *W_ih, *b_ih, *W_hh;
  const float *W_ff1, *b_ff1, *W_ff2, *b_ff2, *W_ta, *b_ta, *W_tb, *b_tb;
  const float *W_o1, *b_o1, *W_o2, *b_o2;
  float *out;
  float *pe;        // [B][TENC][HU] proj_enc (normal stores; wbl2 once after P0)
  float *pd_part;   // [8][B][HU]  (sc1)
  float *e_buf;     // [B][TENC]   (sc1)
  float *ctx;       // [B][HU]     (sc1)
  float *xhat;      // [B][CIN]    (sc1)
  float *hlstm;     // [B][HU]     (sc1)
  float *h_buf;     // [B][HU]     (sc1)
  float *c_buf;     // [B][HU]     (sc1)
  float *hid;       // [B][HU]     (sc1)
  unsigned *bar;    // generation word (own line), memset 0 pre-launch
  unsigned *flags;  // [256*16] per-block arrival flags, 64B stride, memset 0
};

__device__ __forceinline__ float frcp_(float x) { return __builtin_amdgcn_rcpf(x); }
__device__ __forceinline__ float ftanh_(float x) {
  return 1.0f - 2.0f * frcp_(1.0f + __expf(2.0f * x));
}
__device__ __forceinline__ float fsig_(float x) {
  return frcp_(1.0f + __expf(-x));
}

// sc1 (coherence-point) accessors: RELAXED agent atomics. No inv, no wb.
__device__ __forceinline__ float ld_c(const float* p) {
  return __hip_atomic_load(p, __ATOMIC_RELAXED, __HIP_MEMORY_SCOPE_AGENT);
}
__device__ __forceinline__ float2 ld_c2(const float* p) {
  union { ull u; float2 f; } c;
  c.u = __hip_atomic_load((const ull*)p, __ATOMIC_RELAXED, __HIP_MEMORY_SCOPE_AGENT);
  return c.f;
}
__device__ __forceinline__ void st_c(float* p, float v) {
  __hip_atomic_store(p, v, __ATOMIC_RELAXED, __HIP_MEMORY_SCOPE_AGENT);
}

// Flag-array grid barrier, ALL RELAXED. Ordering argument: __syncthreads()
// drains vmcnt(0) (compiler emits waitcnt before s_barrier), so every block's
// sc1 stores are MALL-visible before its flag store. Readers access the same
// data only via sc1 loads -> no L2 staleness anywhere, no fences needed.
__device__ __forceinline__ void gridbar(unsigned* bar, unsigned* flags, unsigned gen) {
  __syncthreads();
  const int t = threadIdx.x;
  if (t == 0) {
    asm volatile("s_waitcnt vmcnt(0) lgkmcnt(0)" ::: "memory");
    __hip_atomic_store(flags + blockIdx.x * 16, gen,
                       __ATOMIC_RELAXED, __HIP_MEMORY_SCOPE_AGENT);
  }
  if (blockIdx.x == 0) {
    while (__hip_atomic_load(flags + t * 16, __ATOMIC_RELAXED,
                             __HIP_MEMORY_SCOPE_AGENT) < gen)
      __builtin_amdgcn_s_sleep(1);
    __syncthreads();
    if (t == 0)
      __hip_atomic_store(bar, gen, __ATOMIC_RELAXED, __HIP_MEMORY_SCOPE_AGENT);
  }
  if (t == 0) {
    while (__hip_atomic_load(bar, __ATOMIC_RELAXED,
                             __HIP_MEMORY_SCOPE_AGENT) < gen)
      __builtin_amdgcn_s_sleep(1);
  }
  __syncthreads();
}

// Stage one 128-wide K slice. A side: whole slice lies on one input (all
// splits are multiples of 128). sc=true -> sc1 8B atomic loads (activations),
// else normal cached float4 loads. W side: normal cached float4 loads.
__device__ __forceinline__ void stage128(
    float (*As)[132], float (*Ws)[132], int arows, int wrows,
    const float* const* wr0, const float* const* wr1, int splitW,
    const float* A0, int lda0, bool s0,
    const float* A1, int lda1, bool s1, int splitA, int kb)
{
  const int t = threadIdx.x;
  const float* A; int lda; bool sc;
  if (kb < splitA) { A = A0 + kb;            lda = lda0; sc = s0; }
  else             { A = A1 + (kb - splitA); lda = lda1; sc = s1; }
  if (sc) {
    for (int idx = t; idx < arows * 64; idx += 256) {
      int r = idx >> 6, kd = (idx & 63) << 1;
      *(float2*)&As[r][kd] = ld_c2(A + r * lda + kd);
    }
  } else {
    for (int idx = t; idx < arows * 32; idx += 256) {
      int r = idx >> 5, kq = (idx & 31) << 2;
      *(float4*)&As[r][kq] = *(const float4*)(A + r * lda + kq);
    }
  }
  const float* const* wr; int ko;
  if (kb < splitW) { wr = wr0; ko = kb; } else { wr = wr1; ko = kb - splitW; }
  for (int idx = t; idx < wrows * 32; idx += 256) {
    int c = idx >> 5, kq = (idx & 31) << 2;
    *(float4*)&Ws[c][kq] = *(const float4*)(wr[c] + ko + kq);
  }
}

// 64x16 output tile, 4 outputs/thread (2 rows x 2 cols).
__device__ __forceinline__ void gemm64x16(
    float (*As)[132], float (*Ws)[132],
    const float* const* wr0, const float* const* wr1, int splitW, const float* biasS,
    const float* A0, int lda0, bool s0, const float* A1, int lda1, bool s1, int splitA,
    int kbase, int klen, float (&acc)[2][2], int& b0o, int& c0o)
{
  const int t = threadIdx.x;
  const int c0 = (t & 7) * 2;
  const int b0 = (t >> 3) * 2;
  __syncthreads();  // tables written; previous-phase LDS readers done
  acc[0][0] = biasS[c0]; acc[0][1] = biasS[c0 + 1];
  acc[1][0] = biasS[c0]; acc[1][1] = biasS[c0 + 1];
  const int ns = klen >> 7;
  for (int s = 0; s < ns; ++s) {
    stage128(As, Ws, 64, 16, wr0, wr1, splitW, A0, lda0, s0, A1, lda1, s1, splitA,
             kbase + (s << 7));
    __syncthreads();
#pragma unroll
    for (int k4 = 0; k4 < 32; ++k4) {
      float4 w0 = *(float4*)&Ws[c0][k4 << 2];
      float4 w1 = *(float4*)&Ws[c0 + 1][k4 << 2];
#pragma unroll
      for (int i = 0; i < 2; ++i) {
        float4 a = *(float4*)&As[b0 + i][k4 << 2];
        acc[i][0] = fmaf(a.x, w0.x, acc[i][0]);
        acc[i][0] = fmaf(a.y, w0.y, acc[i][0]);
        acc[i][0] = fmaf(a.z, w0.z, acc[i][0]);
        acc[i][0] = fmaf(a.w, w0.w, acc[i][0]);
        acc[i][1] = fmaf(a.x, w1.x, acc[i][1]);
        acc[i][1] = fmaf(a.y, w1.y, acc[i][1]);
        acc[i][1] = fmaf(a.z, w1.z, acc[i][1]);
        acc[i][1] = fmaf(a.w, w1.w, acc[i][1]);
      }
    }
    __syncthreads();
  }
  b0o = b0; c0o = c0;
}

// 32x16 output tile, 2 outputs/thread (1 row x 2 cols).
__device__ __forceinline__ void gemm32x16(
    float (*As)[132], float (*Ws)[132],
    const float* const* wr0, const float* const* wr1, int splitW, const float* biasS,
    const float* A0, int lda0, bool s0, const float* A1, int lda1, bool s1, int splitA,
    int kbase, int klen, float (&acc)[2], int& b0o, int& c0o)
{
  const int t = threadIdx.x;
  const int c0 = (t & 7) * 2;
  const int b0 = t >> 3;
  __syncthreads();
  acc[0] = biasS[c0]; acc[1] = biasS[c0 + 1];
  const int ns = klen >> 7;
  for (int s = 0; s < ns; ++s) {
    stage128(As, Ws, 32, 16, wr0, wr1, splitW, A0, lda0, s0, A1, lda1, s1, splitA,
             kbase + (s << 7));
    __syncthreads();
#pragma unroll
    for (int k4 = 0; k4 < 32; ++k4) {
      float4 w0 = *(float4*)&Ws[c0][k4 << 2];
      float4 w1 = *(float4*)&Ws[c0 + 1][k4 << 2];
      float4 a  = *(float4*)&As[b0][k4 << 2];
      acc[0] = fmaf(a.x, w0.x, acc[0]);
      acc[0] = fmaf(a.y, w0.y, acc[0]);
      acc[0] = fmaf(a.z, w0.z, acc[0]);
      acc[0] = fmaf(a.w, w0.w, acc[0]);
      acc[1] = fmaf(a.x, w1.x, acc[1]);
      acc[1] = fmaf(a.y, w1.y, acc[1]);
      acc[1] = fmaf(a.z, w1.z, acc[1]);
      acc[1] = fmaf(a.w, w1.w, acc[1]);
    }
    __syncthreads();
  }
  b0o = b0; c0o = c0;
}

// 64x32 output tile, 8 outputs/thread — P0 only (normal cached A loads).
__device__ __forceinline__ void gemm64x32(
    float (*As)[132], float (*Ws)[132],
    const float* const* wr0, const float* biasS,
    const float* A0, int lda0, int klen, float (&acc)[2][4], int& b0o, int& c0o)
{
  const int t = threadIdx.x;
  const int c0 = (t & 7) * 4;
  const int b0 = (t >> 3) * 2;
  __syncthreads();
#pragma unroll
  for (int i = 0; i < 2; ++i)
#pragma unroll
    for (int j = 0; j < 4; ++j) acc[i][j] = biasS[c0 + j];
  const int ns = klen >> 7;
  for (int s = 0; s < ns; ++s) {
    stage128(As, Ws, 64, 32, wr0, wr0, KBIG, A0, lda0, false, A0, lda0, false, KBIG,
             s << 7);
    __syncthreads();
#pragma unroll
    for (int k4 = 0; k4 < 32; ++k4) {
      float4 w0 = *(float4*)&Ws[c0][k4 << 2];
      float4 w1 = *(float4*)&Ws[c0 + 1][k4 << 2];
      float4 w2 = *(float4*)&Ws[c0 + 2][k4 << 2];
      float4 w3 = *(float4*)&Ws[c0 + 3][k4 << 2];
#pragma unroll
      for (int i = 0; i < 2; ++i) {
        float4 a = *(float4*)&As[b0 + i][k4 << 2];
        acc[i][0] = fmaf(a.x, w0.x, acc[i][0]); acc[i][0] = fmaf(a.y, w0.y, acc[i][0]);
        acc[i][0] = fmaf(a.z, w0.z, acc[i][0]); acc[i][0] = fmaf(a.w, w0.w, acc[i][0]);
        acc[i][1] = fmaf(a.x, w1.x, acc[i][1]); acc[i][1] = fmaf(a.y, w1.y, acc[i][1]);
        acc[i][1] = fmaf(a.z, w1.z, acc[i][1]); acc[i][1] = fmaf(a.w, w1.w, acc[i][1]);
        acc[i][2] = fmaf(a.x, w2.x, acc[i][2]); acc[i][2] = fmaf(a.y, w2.y, acc[i][2]);
        acc[i][2] = fmaf(a.z, w2.z, acc[i][2]); acc[i][2] = fmaf(a.w, w2.w, acc[i][2]);
        acc[i][3] = fmaf(a.x, w3.x, acc[i][3]); acc[i][3] = fmaf(a.y, w3.y, acc[i][3]);
        acc[i][3] = fmaf(a.z, w3.z, acc[i][3]); acc[i][3] = fmaf(a.w, w3.w, acc[i][3]);
      }
    }
    __syncthreads();
  }
  b0o = b0; c0o = c0;
}

__launch_bounds__(256)
__global__ void cfc_kernel(Params P) {
  __shared__ float As[64][132];
  __shared__ float Ws[32][132];
  __shared__ const float* wr0[32];
  __shared__ const float* wr1[32];
  __shared__ float biasS[32];
  __shared__ float misc[1088];

  const int t = threadIdx.x;
  unsigned gen = 1;

  // ---------------- P0: proj_enc (16384 x 512, K=512) + zero h/c ----------------
  for (int job = blockIdx.x; job < 4096 + 32; job += NBLK) {
    if (job < 4096) {
      int rt = job >> 4, ct = job & 15;
      if (t < 32) {
        wr0[t] = P.W_enc + (ct * 32 + t) * HU;
        biasS[t] = P.b_enc[ct * 32 + t];
      }
      float acc[2][4]; int b0, c0;
      gemm64x32(As, Ws, wr0, biasS, P.h_en + rt * 64 * HU, HU, 512, acc, b0, c0);
      float* outp = P.pe + rt * 64 * HU + ct * 32;
#pragma unroll
      for (int i = 0; i < 2; ++i)
#pragma unroll
        for (int j = 0; j < 4; ++j)
          outp[(b0 + i) * HU + c0 + j] = acc[i][j];
    } else {
      int idx = job - 4096;
      float* base = (idx < 16 ? P.h_buf : P.c_buf) + (idx & 15) * 2048;
      for (int i = t; i < 2048; i += 256) st_c(base + i, 0.f);
    }
  }
  // pe was written with normal (cached, writeback) stores: push dirty L2
  // lines to the coherence point once. Readers never cached pe -> no inv.
  __builtin_amdgcn_fence(__ATOMIC_RELEASE, "agent");
  gridbar(P.bar, P.flags, gen++);

  // ---------------- scan over 128 steps ----------------
  for (int step = 0; step < LSEQ; ++step) {
    const float* xt = P.x + step * CIN;  // row b -> + b*(LSEQ*CIN)

    // --- A: proj_dec partials. 256 jobs = 32 col-tiles x 8 K-splits (K=128 each).
    {
      int ut = blockIdx.x & 31, ks = blockIdx.x >> 5;
      if (t < 16) {
        wr0[t] = P.W_dec + (ut * 16 + t) * 1024;
        wr1[t] = wr0[t];
        biasS[t] = 0.f;
      }
      float acc[2][2]; int b0, c0;
      gemm64x16(As, Ws, wr0, wr1, KBIG, biasS,
                P.h_buf, HU, true, P.c_buf, HU, true, 512,
                ks * 128, 128, acc, b0, c0);
      float* outp = P.pd_part + ks * (BSZ * HU) + ut * 16;
      st_c(outp + b0 * HU + c0,           acc[0][0]);
      st_c(outp + b0 * HU + c0 + 1,       acc[0][1]);
      st_c(outp + (b0 + 1) * HU + c0,     acc[1][0]);
      st_c(outp + (b0 + 1) * HU + c0 + 1, acc[1][1]);
    }
    gridbar(P.bar, P.flags, gen++);

    // --- B1: attention logits e[b,t]. 256 jobs = 64 b x 4 t-quarters.
    // pds/wsc skewed (idx = h + (h>>7)) so 4 q-groups hit different banks.
    {
      int b = blockIdx.x >> 2, tq = blockIdx.x & 3;
      float* pds = misc;        // [516] skewed
      float* wsc = misc + 520;  // [516] skewed
      __syncthreads();
      for (int h = t; h < HU; h += 256) {
        float s = 0.f;
#pragma unroll
        for (int p8 = 0; p8 < 8; ++p8) s += ld_c(P.pd_part + p8 * (BSZ * HU) + b * HU + h);
        int hs = h + (h >> 7);
        pds[hs] = s;
        wsc[hs] = P.w_score[h];
      }
      __syncthreads();
      int q = t & 3, tt = tq * 64 + (t >> 2);
      const float* per = P.pe + (b * TENC + tt) * HU + q * 128;
      float acc = 0.f;
      for (int h4 = 0; h4 < 32; ++h4) {
        float4 pv = *(const float4*)(per + h4 * 4);
        int hbs = q * 129 + h4 * 4;
        acc += wsc[hbs + 0] * ftanh_(pds[hbs + 0] + pv.x);
        acc += wsc[hbs + 1] * ftanh_(pds[hbs + 1] + pv.y);
        acc += wsc[hbs + 2] * ftanh_(pds[hbs + 2] + pv.z);
        acc += wsc[hbs + 3] * ftanh_(pds[hbs + 3] + pv.w);
      }
      acc += __shfl_xor(acc, 1);
      acc += __shfl_xor(acc, 2);
      if (q == 0) st_c(P.e_buf + b * TENC + tt, acc);
    }
    gridbar(P.bar, P.flags, gen++);

    // --- B2: softmax (x4 redundant) + context slice. 64 b x 4 m-quarters.
    {
      int b = blockIdx.x >> 2, mq = blockIdx.x & 3;
      float* es = misc;          // [256]
      float* red = misc + 512;   // [8]
      float v = ld_c(P.e_buf + b * TENC + t);
      float m = v;
#pragma unroll
      for (int o = 1; o < 64; o <<= 1) m = fmaxf(m, __shfl_xor(m, o));
      int wid = t >> 6;
      if ((t & 63) == 0) red[wid] = m;
      __syncthreads();
      m = fmaxf(fmaxf(red[0], red[1]), fmaxf(red[2], red[3]));
      float p = __expf(v - m);
      float s = p;
#pragma unroll
      for (int o = 1; o < 64; o <<= 1) s += __shfl_xor(s, o);
      if ((t & 63) == 0) red[4 + wid] = s;
      __syncthreads();
      float sum = (red[4] + red[5]) + (red[6] + red[7]);
      es[t] = p * frcp_(sum);
      __syncthreads();
      if (t < 128) {
        int mcol = mq * 128 + t;
        const float* hb = P.h_en + b * TENC * HU + mcol;
        float a0 = 0.f, a1 = 0.f, a2 = 0.f, a3 = 0.f;
        for (int tt = 0; tt < TENC; tt += 4) {
          a0 = fmaf(es[tt + 0], hb[(tt + 0) * HU], a0);
          a1 = fmaf(es[tt + 1], hb[(tt + 1) * HU], a1);
          a2 = fmaf(es[tt + 2], hb[(tt + 2) * HU], a2);
          a3 = fmaf(es[tt + 3], hb[(tt + 3) * HU], a3);
        }
        st_c(P.ctx + b * HU + mcol, (a0 + a1) + (a2 + a3));
      }
    }
    gridbar(P.bar, P.flags, gen++);

    // --- C: x_hat = [xt|ctx] @ W_yattn^T + b. 16 jobs (64x16, K=768).
    if (blockIdx.x < 16) {
      int ot = blockIdx.x;
      if (t < 16) {
        wr0[t] = P.W_yattn + (ot * 16 + t) * 768;
        wr1[t] = wr0[t];
        biasS[t] = P.b_yattn[ot * 16 + t];
      }
      float acc[2][2]; int b0, c0;
      gemm64x16(As, Ws, wr0, wr1, KBIG, biasS,
                xt, LSEQ * CIN, false, P.ctx, HU, true, 256,
                0, 768, acc, b0, c0);
      float* outp = P.xhat + ot * 16;
      st_c(outp + b0 * CIN + c0,           acc[0][0]);
      st_c(outp + b0 * CIN + c0 + 1,       acc[0][1]);
      st_c(outp + (b0 + 1) * CIN + c0,     acc[1][0]);
      st_c(outp + (b0 + 1) * CIN + c0 + 1, acc[1][1]);
    }
    gridbar(P.bar, P.flags, gen++);

    // --- D: LSTM gates + elementwise. 256 jobs = 2 b-halves x 128 j-quads.
    {
      int bt = blockIdx.x & 1, jq = blockIdx.x >> 1;
      int j0 = jq * 4, rowbase = bt * 32;
      if (t < 16) {
        int jj = t >> 2, g = t & 3;
        int r = g * 512 + j0 + jj;
        wr0[t] = P.W_ih + r * 256;
        wr1[t] = P.W_hh + r * 512;
        biasS[t] = P.b_ih[r];
      }
      float acc[2]; int b0, c0;
      gemm32x16(As, Ws, wr0, wr1, 256, biasS,
                P.xhat + rowbase * CIN, CIN, true,
                P.h_buf + rowbase * HU, HU, true, 256,
                0, 768, acc, b0, c0);
      float* zs = misc;  // [32][16]
      zs[b0 * 16 + c0] = acc[0];
      zs[b0 * 16 + c0 + 1] = acc[1];
      __syncthreads();
      if (t < 128) {
        int b = t >> 2, jj = t & 3;
        int gb = rowbase + b, j = j0 + jj;
        float i_ = zs[b * 16 + jj * 4 + 0];
        float ig = zs[b * 16 + jj * 4 + 1];
        float fg = zs[b * 16 + jj * 4 + 2];
        float og = zs[b * 16 + jj * 4 + 3];
        float cold = ld_c(P.c_buf + gb * HU + j);
        float cn = cold * fsig_(fg + 1.0f) + ftanh_(i_) * fsig_(ig);
        st_c(P.c_buf + gb * HU + j, cn);
        st_c(P.hlstm + gb * HU + j, ftanh_(cn) * fsig_(og));
      }
    }
    gridbar(P.bar, P.flags, gen++);

    // --- E: CfC ff1/ff2/ta/tb + combine -> new h. 256 jobs like D.
    {
      int bt = blockIdx.x & 1, jq = blockIdx.x >> 1;
      int j0 = jq * 4, rowbase = bt * 32;
      if (t < 16) {
        int jj = t >> 2, m = t & 3;
        const float* Wm = (m == 0) ? P.W_ff1 : (m == 1) ? P.W_ff2 : (m == 2) ? P.W_ta : P.W_tb;
        const float* bm = (m == 0) ? P.b_ff1 : (m == 1) ? P.b_ff2 : (m == 2) ? P.b_ta : P.b_tb;
        wr0[t] = Wm + (j0 + jj) * 768;
        wr1[t] = wr0[t];
        biasS[t] = bm[j0 + jj];
      }
      float acc[2]; int b0, c0;
      gemm32x16(As, Ws, wr0, wr1, KBIG, biasS,
                P.xhat + rowbase * CIN, CIN, true,
                P.hlstm + rowbase * HU, HU, true, 256,
                0, 768, acc, b0, c0);
      float* es2 = misc;  // [32][16]
      es2[b0 * 16 + c0] = acc[0];
      es2[b0 * 16 + c0 + 1] = acc[1];
      __syncthreads();
      if (t < 128) {
        int b = t >> 2, jj = t & 3;
        int gb = rowbase + b, j = j0 + jj;
        float ff1 = ftanh_(es2[b * 16 + jj * 4 + 0]);
        float ff2 = ftanh_(es2[b * 16 + jj * 4 + 1]);
        float ta  = es2[b * 16 + jj * 4 + 2];
        float tb  = es2[b * 16 + jj * 4 + 3];
        float ti = fsig_(ta + tb);  // ts = 1.0
        st_c(P.h_buf + gb * HU + j, ff1 * (1.0f - ti) + ti * ff2);
      }
    }
    gridbar(P.bar, P.flags, gen++);
  }

  // ---------------- F1: hid = leaky_relu([h|c_last(ctx)] @ W_o1^T + b). 32 jobs ----------------
  if (blockIdx.x < 32) {
    int ut = blockIdx.x;
    if (t < 16) {
      wr0[t] = P.W_o1 + (ut * 16 + t) * 1024;
      wr1[t] = wr0[t];
      biasS[t] = P.b_o1[ut * 16 + t];
    }
    float acc[2][2]; int b0, c0;
    // reference's c_last is the final attention CONTEXT, not the cell state.
    gemm64x16(As, Ws, wr0, wr1, KBIG, biasS,
              P.h_buf, HU, true, P.ctx, HU, true, 512,
              0, 1024, acc, b0, c0);
    float* outp = P.hid + ut * 16;
#pragma unroll
    for (int i = 0; i < 2; ++i)
#pragma unroll
      for (int j = 0; j < 2; ++j) {
        float v = acc[i][j];
        st_c(outp + (b0 + i) * HU + c0 + j, v > 0.f ? v : 0.01f * v);
      }
  }
  gridbar(P.bar, P.flags, gen++);

  // ---------------- F2: out = hid @ W_o2^T + b (8 jobs) + state copies ----------------
  {
    int job = blockIdx.x;
    if (job < 8) {
      if (t < 16) {
        wr0[t] = P.W_o2 + (job * 16 + t) * HU;
        wr1[t] = wr0[t];
        biasS[t] = P.b_o2[job * 16 + t];
      }
      float acc[2][2]; int b0, c0;
      gemm64x16(As, Ws, wr0, wr1, KBIG, biasS,
                P.hid, HU, true, P.hid, HU, true, KBIG,
                0, 512, acc, b0, c0);
      float* outp = P.out + job * 16;
      outp[b0 * ODIM + c0] = acc[0][0];
      outp[b0 * ODIM + c0 + 1] = acc[0][1];
      outp[(b0 + 1) * ODIM + c0] = acc[1][0];
      outp[(b0 + 1) * ODIM + c0 + 1] = acc[1][1];
    } else if (job < 40) {
      int idx = job - 8;
      const float* src = (idx < 16 ? P.h_buf : P.c_buf) + (idx & 15) * 2048;
      float* dst = P.out + BSZ * ODIM + (idx < 16 ? 0 : BSZ * HU) + (idx & 15) * 2048;
      for (int i = t; i < 1024; i += 256) {
        float2 f = ld_c2(src + 2 * i);
        *(float2*)(dst + 2 * i) = f;
      }
    }
  }
}

extern "C" void kernel_launch(void* const* d_in, const int* in_sizes, int n_in,
                              void* d_out, int out_size, void* d_ws, size_t ws_size,
                              hipStream_t stream) {
  (void)in_sizes; (void)n_in; (void)out_size; (void)ws_size;
  Params P;
  P.x       = (const float*)d_in[0];
  P.h_en    = (const float*)d_in[1];
  P.W_dec   = (const float*)d_in[2];
  P.W_enc   = (const float*)d_in[3];
  P.b_enc   = (const float*)d_in[4];
  P.w_score = (const float*)d_in[5];
  P.W_yattn = (const float*)d_in[6];
  P.b_yattn = (const float*)d_in[7];
  P.W_ih    = (const float*)d_in[8];
  P.b_ih    = (const float*)d_in[9];
  P.W_hh    = (const float*)d_in[10];
  P.W_ff1   = (const float*)d_in[11];
  P.b_ff1   = (const float*)d_in[12];
  P.W_ff2   = (const float*)d_in[13];
  P.b_ff2   = (const float*)d_in[14];
  P.W_ta    = (const float*)d_in[15];
  P.b_ta    = (const float*)d_in[16];
  P.W_tb    = (const float*)d_in[17];
  P.b_tb    = (const float*)d_in[18];
  P.W_o1    = (const float*)d_in[19];
  P.b_o1    = (const float*)d_in[20];
  P.W_o2    = (const float*)d_in[21];
  P.b_o2    = (const float*)d_in[22];
  P.out     = (float*)d_out;

  float* ws = (float*)d_ws;
  size_t off = 0;
  P.pe      = ws + off; off += (size_t)BSZ * TENC * HU;  // 8,388,608 floats
  P.pd_part = ws + off; off += (size_t)8 * BSZ * HU;
  P.e_buf   = ws + off; off += (size_t)BSZ * TENC;
  P.ctx     = ws + off; off += (size_t)BSZ * HU;
  P.xhat    = ws + off; off += (size_t)BSZ * CIN;
  P.hlstm   = ws + off; off += (size_t)BSZ * HU;
  P.h_buf   = ws + off; off += (size_t)BSZ * HU;
  P.c_buf   = ws + off; off += (size_t)BSZ * HU;
  P.hid     = ws + off; off += (size_t)BSZ * HU;
  P.bar     = (unsigned*)(ws + off); off += 16;          // 64B line for gen word
  P.flags   = (unsigned*)(ws + off);                     // 256 x 64B flag slots

  // ws is poisoned 0xAA before every launch: zero barrier gen + flags.
  (void)hipMemsetAsync((void*)P.bar, 0, 64 + 256 * 64, stream);

  hipLaunchKernelGGL(cfc_kernel, dim3(NBLK), dim3(256), 0, stream, P);
}

// Round 6
// 14437.794 us; speedup vs baseline: 3.1903x; 1.2435x over previous
//
#include <hip/hip_runtime.h>

// CfC decoder on MI355X: persistent kernel, 256 blocks x 256 threads (1/CU),
// 128-step scan, grid-wide phases via flag-array barrier.
// Coherence scheme (v3): activations are WRITTEN with relaxed agent atomics
// (sc1 -> MALL, bypassing L2) and READ with normal cached float4 loads; one
// acquire fence (single buffer_inv) per grid barrier drops stale L2 lines.
// This is the cooperative-groups grid.sync() pattern: invalidate once per
// barrier, not once per poll (r2/r4 bug) and no narrow atomic loads (r5 bug).
// fp32 throughout (no fp32 MFMA on CDNA4).

constexpr int BSZ  = 64;
constexpr int LSEQ = 128;
constexpr int TENC = 256;
constexpr int CIN  = 256;
constexpr int HU   = 512;
constexpr int ODIM = 128;
constexpr int NBLK = 256;

struct Params {
  const float *x, *h_en, *W_dec, *W_enc, *b_enc, *w_score, *W_yattn, *b_yattn;
  const float *W_ih, *b_ih, *W_hh;
  const float *W_ff1, *b_ff1, *W_ff2, *b_ff2, *W_ta, *b_ta, *W_tb, *b_tb;
  const float *W_o1, *b_o1, *W_o2, *b_o2;
  float *out;
  float *pe;        // [B][TENC][HU] proj_enc (cached stores + one wbl2)
  float *pd_part;   // [8][B][HU]   sc1 stores
  float *e_buf;     // [B][TENC]    sc1
  float *ctx;       // [B][HU]      sc1
  float *xh_part;   // [2][B][CIN]  sc1 (x_hat K-split partials)
  float *hlstm;     // [B][HU]      sc1
  float *h_buf;     // [B][HU]      sc1
  float *c_buf;     // [B][HU]      sc1
  float *hid;       // [B][HU]      sc1
  unsigned *bar;    // generation word (own line), memset 0 pre-launch
  unsigned *flags;  // [256*16] per-block arrival flags, 64B stride, memset 0
};

__device__ __forceinline__ float frcp_(float x) { return __builtin_amdgcn_rcpf(x); }
__device__ __forceinline__ float ftanh_(float x) {
  return 1.0f - 2.0f * frcp_(1.0f + __expf(2.0f * x));
}
__device__ __forceinline__ float fsig_(float x) {
  return frcp_(1.0f + __expf(-x));
}

__device__ __forceinline__ void st_c(float* p, float v) {
  __hip_atomic_store(p, v, __ATOMIC_RELAXED, __HIP_MEMORY_SCOPE_AGENT);
}

// Flag-array grid barrier. Relaxed polling (no per-poll inv); ONE acquire
// fence after poll success (single L1/L2 invalidate). Producer side: sc1
// stores reach MALL before the flag store (waitcnt drain).
__device__ __forceinline__ void gridbar(unsigned* bar, unsigned* flags, unsigned gen) {
  __syncthreads();
  const int t = threadIdx.x;
  if (t == 0) {
    asm volatile("s_waitcnt vmcnt(0) lgkmcnt(0)" ::: "memory");
    __hip_atomic_store(flags + blockIdx.x * 16, gen,
                       __ATOMIC_RELAXED, __HIP_MEMORY_SCOPE_AGENT);
  }
  if (blockIdx.x == 0) {
    while (__hip_atomic_load(flags + t * 16, __ATOMIC_RELAXED,
                             __HIP_MEMORY_SCOPE_AGENT) < gen)
      __builtin_amdgcn_s_sleep(1);
    __syncthreads();
    if (t == 0)
      __hip_atomic_store(bar, gen, __ATOMIC_RELAXED, __HIP_MEMORY_SCOPE_AGENT);
  }
  if (t == 0) {
    while (__hip_atomic_load(bar, __ATOMIC_RELAXED,
                             __HIP_MEMORY_SCOPE_AGENT) < gen)
      __builtin_amdgcn_s_sleep(1);
    __builtin_amdgcn_fence(__ATOMIC_ACQUIRE, "agent");  // ONE inv per barrier
  }
  __syncthreads();
}

// ---- inner-product helpers on LDS tiles (row stride passed via pointers) ----
__device__ __forceinline__ void dot2x2(const float* A0, const float* A1,
                                       const float* W0, const float* W1,
                                       int nk4, float (&acc)[2][2]) {
#pragma unroll 8
  for (int k4 = 0; k4 < nk4; ++k4) {
    float4 w0 = *(const float4*)(W0 + (k4 << 2));
    float4 w1 = *(const float4*)(W1 + (k4 << 2));
    float4 a0 = *(const float4*)(A0 + (k4 << 2));
    float4 a1 = *(const float4*)(A1 + (k4 << 2));
    acc[0][0] = fmaf(a0.x, w0.x, acc[0][0]); acc[0][0] = fmaf(a0.y, w0.y, acc[0][0]);
    acc[0][0] = fmaf(a0.z, w0.z, acc[0][0]); acc[0][0] = fmaf(a0.w, w0.w, acc[0][0]);
    acc[0][1] = fmaf(a0.x, w1.x, acc[0][1]); acc[0][1] = fmaf(a0.y, w1.y, acc[0][1]);
    acc[0][1] = fmaf(a0.z, w1.z, acc[0][1]); acc[0][1] = fmaf(a0.w, w1.w, acc[0][1]);
    acc[1][0] = fmaf(a1.x, w0.x, acc[1][0]); acc[1][0] = fmaf(a1.y, w0.y, acc[1][0]);
    acc[1][0] = fmaf(a1.z, w0.z, acc[1][0]); acc[1][0] = fmaf(a1.w, w0.w, acc[1][0]);
    acc[1][1] = fmaf(a1.x, w1.x, acc[1][1]); acc[1][1] = fmaf(a1.y, w1.y, acc[1][1]);
    acc[1][1] = fmaf(a1.z, w1.z, acc[1][1]); acc[1][1] = fmaf(a1.w, w1.w, acc[1][1]);
  }
}

__device__ __forceinline__ void dot1x2(const float* A0,
                                       const float* W0, const float* W1,
                                       int nk4, float (&acc)[2]) {
#pragma unroll 8
  for (int k4 = 0; k4 < nk4; ++k4) {
    float4 w0 = *(const float4*)(W0 + (k4 << 2));
    float4 w1 = *(const float4*)(W1 + (k4 << 2));
    float4 a  = *(const float4*)(A0 + (k4 << 2));
    acc[0] = fmaf(a.x, w0.x, acc[0]); acc[0] = fmaf(a.y, w0.y, acc[0]);
    acc[0] = fmaf(a.z, w0.z, acc[0]); acc[0] = fmaf(a.w, w0.w, acc[0]);
    acc[1] = fmaf(a.x, w1.x, acc[1]); acc[1] = fmaf(a.y, w1.y, acc[1]);
    acc[1] = fmaf(a.z, w1.z, acc[1]); acc[1] = fmaf(a.w, w1.w, acc[1]);
  }
}

__device__ __forceinline__ void dot2x4(const float* A0, const float* A1,
                                       const float* W0, const float* W1,
                                       const float* W2, const float* W3,
                                       int nk4, float (&acc)[2][4]) {
#pragma unroll 4
  for (int k4 = 0; k4 < nk4; ++k4) {
    float4 w0 = *(const float4*)(W0 + (k4 << 2));
    float4 w1 = *(const float4*)(W1 + (k4 << 2));
    float4 w2 = *(const float4*)(W2 + (k4 << 2));
    float4 w3 = *(const float4*)(W3 + (k4 << 2));
#pragma unroll
    for (int i = 0; i < 2; ++i) {
      float4 a = *(const float4*)((i ? A1 : A0) + (k4 << 2));
      acc[i][0] = fmaf(a.x, w0.x, acc[i][0]); acc[i][0] = fmaf(a.y, w0.y, acc[i][0]);
      acc[i][0] = fmaf(a.z, w0.z, acc[i][0]); acc[i][0] = fmaf(a.w, w0.w, acc[i][0]);
      acc[i][1] = fmaf(a.x, w1.x, acc[i][1]); acc[i][1] = fmaf(a.y, w1.y, acc[i][1]);
      acc[i][1] = fmaf(a.z, w1.z, acc[i][1]); acc[i][1] = fmaf(a.w, w1.w, acc[i][1]);
      acc[i][2] = fmaf(a.x, w2.x, acc[i][2]); acc[i][2] = fmaf(a.y, w2.y, acc[i][2]);
      acc[i][2] = fmaf(a.z, w2.z, acc[i][2]); acc[i][2] = fmaf(a.w, w2.w, acc[i][2]);
      acc[i][3] = fmaf(a.x, w3.x, acc[i][3]); acc[i][3] = fmaf(a.y, w3.y, acc[i][3]);
      acc[i][3] = fmaf(a.z, w3.z, acc[i][3]); acc[i][3] = fmaf(a.w, w3.w, acc[i][3]);
    }
  }
}

__launch_bounds__(256)
__global__ void cfc_kernel(Params P) {
  __shared__ float lds[12800];          // 51.2 KB, reused per phase
  __shared__ const float* wrA[32];
  __shared__ const float* wrB[32];
  __shared__ float biasS[32];

  const int t = threadIdx.x;
  unsigned gen = 1;

  // ---------- P0: proj_enc (16384x512, K=512) + zero h/c ----------
  // Job map: rt = job&255 fixed per block -> its h_en tile stays L2-resident.
  for (int job = blockIdx.x; job < 4096 + 32; job += NBLK) {
    if (job < 4096) {
      int rt = job & 255, ct = job >> 8;          // 64-row x 32-col tiles
      if (t < 32) {
        wrA[t] = P.W_enc + (ct * 32 + t) * HU;
        biasS[t] = P.b_enc[ct * 32 + t];
      }
      const int c0 = (t & 7) * 4, b0 = (t >> 3) * 2;
      __syncthreads();
      float acc[2][4];
#pragma unroll
      for (int i = 0; i < 2; ++i)
#pragma unroll
        for (int j = 0; j < 4; ++j) acc[i][j] = biasS[c0 + j];
      const float* Ab = P.h_en + (size_t)(rt * 64) * HU;
      for (int s = 0; s < 4; ++s) {
        int ko = s * 128;
        for (int idx = t; idx < 2048; idx += 256) {
          int r = idx >> 5, c4 = idx & 31;
          *(float4*)&lds[r * 132 + (c4 << 2)] =
            *(const float4*)(Ab + (size_t)r * HU + ko + (c4 << 2));
        }
        for (int idx = t; idx < 1024; idx += 256) {
          int r = idx >> 5, c4 = idx & 31;
          *(float4*)&lds[8448 + r * 132 + (c4 << 2)] =
            *(const float4*)(wrA[r] + ko + (c4 << 2));
        }
        __syncthreads();
        dot2x4(&lds[b0 * 132], &lds[(b0 + 1) * 132],
               &lds[8448 + c0 * 132], &lds[8448 + (c0 + 1) * 132],
               &lds[8448 + (c0 + 2) * 132], &lds[8448 + (c0 + 3) * 132], 32, acc);
        __syncthreads();
      }
      float* outp = P.pe + (size_t)(rt * 64) * HU + ct * 32;
#pragma unroll
      for (int i = 0; i < 2; ++i)
#pragma unroll
        for (int j = 0; j < 4; ++j)
          outp[(b0 + i) * HU + c0 + j] = acc[i][j];
    } else {
      int idx = job - 4096;
      float* base = (idx < 16 ? P.h_buf : P.c_buf) + (idx & 15) * 2048;
      for (int i = t; i < 2048; i += 256) st_c(base + i, 0.f);
    }
  }
  // pe used cached stores: push dirty L2 to MALL once.
  __builtin_amdgcn_fence(__ATOMIC_RELEASE, "agent");
  gridbar(P.bar, P.flags, gen++);

  // ---------- scan over 128 steps ----------
  for (int step = 0; step < LSEQ; ++step) {

    // --- A: proj_dec partials. 256 jobs = 32 col-tiles x 8 K-splits (K=128).
    {
      int ut = blockIdx.x & 31, ks = blockIdx.x >> 5;
      if (t < 16) wrA[t] = P.W_dec + (ut * 16 + t) * 1024 + ks * 128;
      const int c0 = (t & 7) * 2, b0 = (t >> 3) * 2;
      const float* Asrc = (ks < 4) ? (P.h_buf + ks * 128) : (P.c_buf + (ks - 4) * 128);
      __syncthreads();
      float acc[2][2] = {{0.f, 0.f}, {0.f, 0.f}};
      for (int idx = t; idx < 2048; idx += 256) {
        int r = idx >> 5, c4 = idx & 31;
        *(float4*)&lds[r * 132 + (c4 << 2)] =
          *(const float4*)(Asrc + r * HU + (c4 << 2));
      }
      for (int idx = t; idx < 512; idx += 256) {
        int r = idx >> 5, c4 = idx & 31;
        *(float4*)&lds[8448 + r * 132 + (c4 << 2)] =
          *(const float4*)(wrA[r] + (c4 << 2));
      }
      __syncthreads();
      dot2x2(&lds[b0 * 132], &lds[(b0 + 1) * 132],
             &lds[8448 + c0 * 132], &lds[8448 + (c0 + 1) * 132], 32, acc);
      float* outp = P.pd_part + ks * (BSZ * HU) + ut * 16;
      st_c(outp + b0 * HU + c0,           acc[0][0]);
      st_c(outp + b0 * HU + c0 + 1,       acc[0][1]);
      st_c(outp + (b0 + 1) * HU + c0,     acc[1][0]);
      st_c(outp + (b0 + 1) * HU + c0 + 1, acc[1][1]);
    }
    gridbar(P.bar, P.flags, gen++);

    // --- B1: attention logits. 256 jobs = 64 b x 4 t-quarters.
    // pds/wsc skewed (idx = h + (h>>7)) to spread q-groups across banks.
    {
      int b = blockIdx.x >> 2, tq = blockIdx.x & 3;
      float* pds = lds;         // [516] skewed
      float* wsc = lds + 520;   // [516] skewed
      __syncthreads();
      {
        int h = t * 2;
        float sx = 0.f, sy = 0.f;
#pragma unroll
        for (int p8 = 0; p8 < 8; ++p8) {
          float2 v = *(const float2*)(P.pd_part + p8 * (BSZ * HU) + b * HU + h);
          sx += v.x; sy += v.y;
        }
        int hs = h + (h >> 7);
        pds[hs] = sx; pds[hs + 1] = sy;
        float2 w = *(const float2*)(P.w_score + h);
        wsc[hs] = w.x; wsc[hs + 1] = w.y;
      }
      __syncthreads();
      int q = t & 3, tt = tq * 64 + (t >> 2);
      const float* per = P.pe + (size_t)(b * TENC + tt) * HU + q * 128;
      const float* pd = pds + q * 129;
      const float* wv = wsc + q * 129;
      float acc = 0.f;
      for (int h4 = 0; h4 < 32; ++h4) {
        float4 pv = *(const float4*)(per + (h4 << 2));
        int o = h4 << 2;
        acc += wv[o + 0] * ftanh_(pd[o + 0] + pv.x);
        acc += wv[o + 1] * ftanh_(pd[o + 1] + pv.y);
        acc += wv[o + 2] * ftanh_(pd[o + 2] + pv.z);
        acc += wv[o + 3] * ftanh_(pd[o + 3] + pv.w);
      }
      acc += __shfl_xor(acc, 1);
      acc += __shfl_xor(acc, 2);
      if (q == 0) st_c(P.e_buf + b * TENC + tt, acc);
    }
    gridbar(P.bar, P.flags, gen++);

    // --- B2: softmax (x4 redundant) + context slice. 64 b x 4 m-quarters.
    {
      int b = blockIdx.x >> 2, mq = blockIdx.x & 3;
      float* es = lds;          // [256]
      float* red = lds + 260;   // [8]
      float v = P.e_buf[b * TENC + t];
      float m = v;
#pragma unroll
      for (int o = 1; o < 64; o <<= 1) m = fmaxf(m, __shfl_xor(m, o));
      int wid = t >> 6;
      if ((t & 63) == 0) red[wid] = m;
      __syncthreads();
      m = fmaxf(fmaxf(red[0], red[1]), fmaxf(red[2], red[3]));
      float p = __expf(v - m);
      float s = p;
#pragma unroll
      for (int o = 1; o < 64; o <<= 1) s += __shfl_xor(s, o);
      if ((t & 63) == 0) red[4 + wid] = s;
      __syncthreads();
      float sum = (red[4] + red[5]) + (red[6] + red[7]);
      es[t] = p * frcp_(sum);
      __syncthreads();
      if (t < 128) {
        int mcol = mq * 128 + t;
        const float* hb = P.h_en + (size_t)b * TENC * HU + mcol;
        float a0 = 0.f, a1 = 0.f, a2 = 0.f, a3 = 0.f;
        for (int tt = 0; tt < TENC; tt += 4) {
          a0 = fmaf(es[tt + 0], hb[(tt + 0) * HU], a0);
          a1 = fmaf(es[tt + 1], hb[(tt + 1) * HU], a1);
          a2 = fmaf(es[tt + 2], hb[(tt + 2) * HU], a2);
          a3 = fmaf(es[tt + 3], hb[(tt + 3) * HU], a3);
        }
        st_c(P.ctx + b * HU + mcol, (a0 + a1) + (a2 + a3));
      }
    }
    gridbar(P.bar, P.flags, gen++);

    // --- C: x_hat partials. 32 jobs = 16 col-tiles x 2 K-splits (K=384, 3x128).
    if (blockIdx.x < 32) {
      int ct = blockIdx.x & 15, ks = blockIdx.x >> 4;
      if (t < 16) {
        wrA[t] = P.W_yattn + (ct * 16 + t) * 768 + ks * 384;
        biasS[t] = ks ? 0.f : P.b_yattn[ct * 16 + t];
      }
      const int c0 = (t & 7) * 2, b0 = (t >> 3) * 2;
      __syncthreads();
      float acc[2][2];
      acc[0][0] = biasS[c0]; acc[0][1] = biasS[c0 + 1];
      acc[1][0] = biasS[c0]; acc[1][1] = biasS[c0 + 1];
      for (int s = 0; s < 3; ++s) {
        int k = ks * 384 + s * 128;
        for (int idx = t; idx < 2048; idx += 256) {
          int r = idx >> 5, c4 = idx & 31;
          const float* src = (k < 256)
            ? (P.x + ((size_t)r * LSEQ + step) * CIN + k)
            : (P.ctx + r * HU + (k - 256));
          *(float4*)&lds[r * 132 + (c4 << 2)] = *(const float4*)(src + (c4 << 2));
        }
        for (int idx = t; idx < 512; idx += 256) {
          int r = idx >> 5, c4 = idx & 31;
          *(float4*)&lds[8448 + r * 132 + (c4 << 2)] =
            *(const float4*)(wrA[r] + s * 128 + (c4 << 2));
        }
        __syncthreads();
        dot2x2(&lds[b0 * 132], &lds[(b0 + 1) * 132],
               &lds[8448 + c0 * 132], &lds[8448 + (c0 + 1) * 132], 32, acc);
        __syncthreads();
      }
      float* outp = P.xh_part + ks * (BSZ * CIN) + ct * 16;
      st_c(outp + b0 * CIN + c0,           acc[0][0]);
      st_c(outp + b0 * CIN + c0 + 1,       acc[0][1]);
      st_c(outp + (b0 + 1) * CIN + c0,     acc[1][0]);
      st_c(outp + (b0 + 1) * CIN + c0 + 1, acc[1][1]);
    }
    gridbar(P.bar, P.flags, gen++);

    // --- D: LSTM gates + elementwise. 256 jobs, 32x16 tiles, K=768 (3x256).
    {
      int bt = blockIdx.x & 1, jq = blockIdx.x >> 1;
      int j0 = jq * 4, rowbase = bt * 32;
      if (t < 16) {
        int jj = t >> 2, g = t & 3;
        int r = g * 512 + j0 + jj;
        wrA[t] = P.W_ih + r * 256;
        wrB[t] = P.W_hh + (size_t)r * 512;
        biasS[t] = P.b_ih[r];
      }
      const int c0 = (t & 7) * 2, b0 = t >> 3;
      __syncthreads();
      float acc[2];
      acc[0] = biasS[c0]; acc[1] = biasS[c0 + 1];
      for (int s = 0; s < 3; ++s) {
        if (s == 0) {  // x_hat = part0 + part1
          for (int idx = t; idx < 2048; idx += 256) {
            int r = idx >> 6, c4 = idx & 63; int gb = rowbase + r;
            float4 a = *(const float4*)(P.xh_part + gb * CIN + (c4 << 2));
            float4 b2 = *(const float4*)(P.xh_part + BSZ * CIN + gb * CIN + (c4 << 2));
            a.x += b2.x; a.y += b2.y; a.z += b2.z; a.w += b2.w;
            *(float4*)&lds[r * 260 + (c4 << 2)] = a;
          }
          for (int idx = t; idx < 1024; idx += 256) {
            int r = idx >> 6, c4 = idx & 63;
            *(float4*)&lds[8320 + r * 260 + (c4 << 2)] =
              *(const float4*)(wrA[r] + (c4 << 2));
          }
        } else {
          int ho = (s - 1) * 256;
          for (int idx = t; idx < 2048; idx += 256) {
            int r = idx >> 6, c4 = idx & 63; int gb = rowbase + r;
            *(float4*)&lds[r * 260 + (c4 << 2)] =
              *(const float4*)(P.h_buf + gb * HU + ho + (c4 << 2));
          }
          for (int idx = t; idx < 1024; idx += 256) {
            int r = idx >> 6, c4 = idx & 63;
            *(float4*)&lds[8320 + r * 260 + (c4 << 2)] =
              *(const float4*)(wrB[r] + ho + (c4 << 2));
          }
        }
        __syncthreads();
        dot1x2(&lds[b0 * 260], &lds[8320 + c0 * 260], &lds[8320 + (c0 + 1) * 260], 64, acc);
        __syncthreads();
      }
      float* zs = lds;  // reuse (post-sync)
      zs[b0 * 16 + c0] = acc[0];
      zs[b0 * 16 + c0 + 1] = acc[1];
      __syncthreads();
      if (t < 128) {
        int b2 = t >> 2, jj = t & 3;
        int gb = rowbase + b2, j = j0 + jj;
        float i_ = zs[b2 * 16 + jj * 4 + 0];
        float ig = zs[b2 * 16 + jj * 4 + 1];
        float fg = zs[b2 * 16 + jj * 4 + 2];
        float og = zs[b2 * 16 + jj * 4 + 3];
        float cold = P.c_buf[gb * HU + j];
        float cn = cold * fsig_(fg + 1.0f) + ftanh_(i_) * fsig_(ig);
        st_c(P.c_buf + gb * HU + j, cn);
        st_c(P.hlstm + gb * HU + j, ftanh_(cn) * fsig_(og));
      }
    }
    gridbar(P.bar, P.flags, gen++);

    // --- E: CfC ff1/ff2/ta/tb + combine. 256 jobs, 32x16, K=768 (3x256).
    {
      int bt = blockIdx.x & 1, jq = blockIdx.x >> 1;
      int j0 = jq * 4, rowbase = bt * 32;
      if (t < 16) {
        int jj = t >> 2, m = t & 3;
        const float* Wm = (m == 0) ? P.W_ff1 : (m == 1) ? P.W_ff2 : (m == 2) ? P.W_ta : P.W_tb;
        const float* bm = (m == 0) ? P.b_ff1 : (m == 1) ? P.b_ff2 : (m == 2) ? P.b_ta : P.b_tb;
        wrA[t] = Wm + (j0 + jj) * 768;
        biasS[t] = bm[j0 + jj];
      }
      const int c0 = (t & 7) * 2, b0 = t >> 3;
      __syncthreads();
      float acc[2];
      acc[0] = biasS[c0]; acc[1] = biasS[c0 + 1];
      for (int s = 0; s < 3; ++s) {
        if (s == 0) {
          for (int idx = t; idx < 2048; idx += 256) {
            int r = idx >> 6, c4 = idx & 63; int gb = rowbase + r;
            float4 a = *(const float4*)(P.xh_part + gb * CIN + (c4 << 2));
            float4 b2 = *(const float4*)(P.xh_part + BSZ * CIN + gb * CIN + (c4 << 2));
            a.x += b2.x; a.y += b2.y; a.z += b2.z; a.w += b2.w;
            *(float4*)&lds[r * 260 + (c4 << 2)] = a;
          }
        } else {
          int ho = (s - 1) * 256;
          for (int idx = t; idx < 2048; idx += 256) {
            int r = idx >> 6, c4 = idx & 63; int gb = rowbase + r;
            *(float4*)&lds[r * 260 + (c4 << 2)] =
              *(const float4*)(P.hlstm + gb * HU + ho + (c4 << 2));
          }
        }
        for (int idx = t; idx < 1024; idx += 256) {
          int r = idx >> 6, c4 = idx & 63;
          *(float4*)&lds[8320 + r * 260 + (c4 << 2)] =
            *(const float4*)(wrA[r] + s * 256 + (c4 << 2));
        }
        __syncthreads();
        dot1x2(&lds[b0 * 260], &lds[8320 + c0 * 260], &lds[8320 + (c0 + 1) * 260], 64, acc);
        __syncthreads();
      }
      float* es2 = lds;
      es2[b0 * 16 + c0] = acc[0];
      es2[b0 * 16 + c0 + 1] = acc[1];
      __syncthreads();
      if (t < 128) {
        int b2 = t >> 2, jj = t & 3;
        int gb = rowbase + b2, j = j0 + jj;
        float ff1 = ftanh_(es2[b2 * 16 + jj * 4 + 0]);
        float ff2 = ftanh_(es2[b2 * 16 + jj * 4 + 1]);
        float ta  = es2[b2 * 16 + jj * 4 + 2];
        float tb  = es2[b2 * 16 + jj * 4 + 3];
        float ti = fsig_(ta + tb);  // ts = 1.0
        st_c(P.h_buf + gb * HU + j, ff1 * (1.0f - ti) + ti * ff2);
      }
    }
    gridbar(P.bar, P.flags, gen++);
  }

  // ---------- F1: hid = leaky_relu([h|ctx] @ W_o1^T + b). 64 jobs, 32x16 ----------
  if (blockIdx.x < 64) {
    int bt = blockIdx.x & 1, ut = blockIdx.x >> 1;
    int rowbase = bt * 32;
    if (t < 16) {
      wrA[t] = P.W_o1 + (ut * 16 + t) * 1024;
      biasS[t] = P.b_o1[ut * 16 + t];
    }
    const int c0 = (t & 7) * 2, b0 = t >> 3;
    __syncthreads();
    float acc[2];
    acc[0] = biasS[c0]; acc[1] = biasS[c0 + 1];
    for (int s = 0; s < 4; ++s) {
      const float* src = (s < 2) ? (P.h_buf + s * 256) : (P.ctx + (s - 2) * 256);
      for (int idx = t; idx < 2048; idx += 256) {
        int r = idx >> 6, c4 = idx & 63; int gb = rowbase + r;
        *(float4*)&lds[r * 260 + (c4 << 2)] = *(const float4*)(src + gb * HU + (c4 << 2));
      }
      for (int idx = t; idx < 1024; idx += 256) {
        int r = idx >> 6, c4 = idx & 63;
        *(float4*)&lds[8320 + r * 260 + (c4 << 2)] =
          *(const float4*)(wrA[r] + s * 256 + (c4 << 2));
      }
      __syncthreads();
      dot1x2(&lds[b0 * 260], &lds[8320 + c0 * 260], &lds[8320 + (c0 + 1) * 260], 64, acc);
      __syncthreads();
    }
#pragma unroll
    for (int j = 0; j < 2; ++j) {
      float v = acc[j];
      st_c(P.hid + (rowbase + b0) * HU + ut * 16 + c0 + j, v > 0.f ? v : 0.01f * v);
    }
  }
  gridbar(P.bar, P.flags, gen++);

  // ---------- F2: out = hid @ W_o2^T + b (16 jobs) + state copies ----------
  {
    int job = blockIdx.x;
    if (job < 16) {
      int bt = job & 1, ot = job >> 1;
      int rowbase = bt * 32;
      if (t < 16) {
        wrA[t] = P.W_o2 + (ot * 16 + t) * HU;
        biasS[t] = P.b_o2[ot * 16 + t];
      }
      const int c0 = (t & 7) * 2, b0 = t >> 3;
      __syncthreads();
      float acc[2];
      acc[0] = biasS[c0]; acc[1] = biasS[c0 + 1];
      for (int s = 0; s < 2; ++s) {
        for (int idx = t; idx < 2048; idx += 256) {
          int r = idx >> 6, c4 = idx & 63; int gb = rowbase + r;
          *(float4*)&lds[r * 260 + (c4 << 2)] =
            *(const float4*)(P.hid + gb * HU + s * 256 + (c4 << 2));
        }
        for (int idx = t; idx < 1024; idx += 256) {
          int r = idx >> 6, c4 = idx & 63;
          *(float4*)&lds[8320 + r * 260 + (c4 << 2)] =
            *(const float4*)(wrA[r] + s * 256 + (c4 << 2));
        }
        __syncthreads();
        dot1x2(&lds[b0 * 260], &lds[8320 + c0 * 260], &lds[8320 + (c0 + 1) * 260], 64, acc);
        __syncthreads();
      }
      P.out[(rowbase + b0) * ODIM + ot * 16 + c0]     = acc[0];
      P.out[(rowbase + b0) * ODIM + ot * 16 + c0 + 1] = acc[1];
    } else if (job < 48) {
      int idx = job - 16;
      const float* src = (idx < 16 ? P.h_buf : P.c_buf) + (idx & 15) * 2048;
      float* dst = P.out + BSZ * ODIM + (idx < 16 ? 0 : BSZ * HU) + (idx & 15) * 2048;
      for (int i = t; i < 512; i += 256)
        *(float4*)(dst + 4 * i) = *(const float4*)(src + 4 * i);
    }
  }
}

extern "C" void kernel_launch(void* const* d_in, const int* in_sizes, int n_in,
                              void* d_out, int out_size, void* d_ws, size_t ws_size,
                              hipStream_t stream) {
  (void)in_sizes; (void)n_in; (void)out_size; (void)ws_size;
  Params P;
  P.x       = (const float*)d_in[0];
  P.h_en    = (const float*)d_in[1];
  P.W_dec   = (const float*)d_in[2];
  P.W_enc   = (const float*)d_in[3];
  P.b_enc   = (const float*)d_in[4];
  P.w_score = (const float*)d_in[5];
  P.W_yattn = (const float*)d_in[6];
  P.b_yattn = (const float*)d_in[7];
  P.W_ih    = (const float*)d_in[8];
  P.b_ih    = (const float*)d_in[9];
  P.W_hh    = (const float*)d_in[10];
  P.W_ff1   = (const float*)d_in[11];
  P.b_ff1   = (const float*)d_in[12];
  P.W_ff2   = (const float*)d_in[13];
  P.b_ff2   = (const float*)d_in[14];
  P.W_ta    = (const float*)d_in[15];
  P.b_ta    = (const float*)d_in[16];
  P.W_tb    = (const float*)d_in[17];
  P.b_tb    = (const float*)d_in[18];
  P.W_o1    = (const float*)d_in[19];
  P.b_o1    = (const float*)d_in[20];
  P.W_o2    = (const float*)d_in[21];
  P.b_o2    = (const float*)d_in[22];
  P.out     = (float*)d_out;

  float* ws = (float*)d_ws;
  size_t off = 0;
  P.pe      = ws + off; off += (size_t)BSZ * TENC * HU;   // 8,388,608
  P.pd_part = ws + off; off += (size_t)8 * BSZ * HU;      // 262,144
  P.e_buf   = ws + off; off += (size_t)BSZ * TENC;        // 16,384
  P.ctx     = ws + off; off += (size_t)BSZ * HU;          // 32,768
  P.xh_part = ws + off; off += (size_t)2 * BSZ * CIN;     // 32,768
  P.hlstm   = ws + off; off += (size_t)BSZ * HU;
  P.h_buf   = ws + off; off += (size_t)BSZ * HU;
  P.c_buf   = ws + off; off += (size_t)BSZ * HU;
  P.hid     = ws + off; off += (size_t)BSZ * HU;
  P.bar     = (unsigned*)(ws + off); off += 16;           // 64B line
  P.flags   = (unsigned*)(ws + off);                      // 256 x 64B

  // ws is poisoned 0xAA before every launch: zero barrier gen + flags.
  (void)hipMemsetAsync((void*)P.bar, 0, 64 + 256 * 64, stream);

  hipLaunchKernelGGL(cfc_kernel, dim3(NBLK), dim3(256), 0, stream, P);
}